// Round 4
// baseline (327.807 us; speedup 1.0000x reference)
//
#include <hip/hip_runtime.h>

// RouterAttention on gfx950. B=4 L=S=4096 D=512 H=8 E=R=64.
// R4: (1) XOR-swizzled global->LDS staging in gemm_fused (coalesced 128B
// segments + conflict-free ds_read); (2) exp fused into rscore (no softmax
// kernel, E bf16 + row sums via atomics; safe: scores ~N(0,1)); (3) final_attn
// quad-per-token in-thread softmax.

#define DEV __device__ __forceinline__

constexpr int Bn = 4, Ln = 4096, Dn = 512, Hn = 8, En = 64, Rn = 64;
constexpr int Sn = 4096;
constexpr float SCALE = 0.125f;                 // 1/sqrt(E)
constexpr float L2B_OVER_K = 13.287712379549449f / 32.0f; // log2(10000)/32

typedef __bf16 bf16x8 __attribute__((ext_vector_type(8)));
typedef float floatx4 __attribute__((ext_vector_type(4)));

DEV float bf2f(ushort u) { return __uint_as_float(((unsigned)u) << 16); }
DEV ushort f2bf(float f) {
    unsigned u = __float_as_uint(f);
    u += 0x7fffu + ((u >> 16) & 1u);            // RNE
    return (ushort)(u >> 16);
}
DEV bf16x8 ldsfrag(const ushort* p) { return *reinterpret_cast<const bf16x8*>(p); }
#define MFMA(a, b, c) __builtin_amdgcn_mfma_f32_16x16x32_bf16(a, b, c, 0, 0, 0)

DEV void gload16(const ushort* g, ushort* lds) {
    __builtin_amdgcn_global_load_lds(
        (const __attribute__((address_space(1))) unsigned int*)g,
        (__attribute__((address_space(3))) unsigned int*)lds, 16, 0, 0);
}

DEV float wave_sum(float v) {
    #pragma unroll
    for (int off = 1; off < 64; off <<= 1) v += __shfl_xor(v, off);
    return v;
}
DEV int wave_sum_i(int v) {
    #pragma unroll
    for (int off = 1; off < 64; off <<= 1) v += __shfl_xor(v, off);
    return v;
}

// ---- dtype sniffer: flag=1 if x looks like f32, 0 if bf16-packed ----
__global__ __launch_bounds__(256) void sniff_k(const uint* __restrict__ x, int* __restrict__ flag) {
    int t = threadIdx.x, cnt = 0;
    #pragma unroll
    for (int i = 0; i < 16; ++i) {
        uint u = x[t * 16 + i];
        uint e = (u >> 7) & 0xFF;
        cnt += (e >= 100 && e <= 140) ? 1 : 0;
    }
    cnt = wave_sum_i(cnt);
    __shared__ int red[4];
    int w = t >> 6, l = t & 63;
    if (l == 0) red[w] = cnt;
    __syncthreads();
    if (t == 0) flag[0] = ((red[0] + red[1] + red[2] + red[3]) < 2048) ? 1 : 0;
}

// ---- canonicalize all 10 inputs into contiguous bf16 region ----
constexpr size_t SEG1 = 8388608, SEG2 = 8650752, SEG3 = 8651264, SEG4 = 8913408,
                 SEG5 = 8913920, SEG6 = 9176064, SEG7 = 9176576, SEG8 = 9438720,
                 SEG9 = 9439232, SEGT = 9472000;
__global__ __launch_bounds__(256)
void canon_k(const void* p0, const void* p1, const void* p2, const void* p3,
             const void* p4, const void* p5, const void* p6, const void* p7,
             const void* p8, const void* p9, const int* __restrict__ flag,
             ushort* __restrict__ dst) {
    const int f = *flag;
    size_t i0 = (size_t)blockIdx.x * 1024 + threadIdx.x;
    #pragma unroll
    for (int r = 0; r < 4; ++r) {
        size_t i = i0 + (size_t)r * 256;
        if (i >= SEGT) return;
        const void* sp; size_t off;
        if      (i < SEG1) { sp = p0; off = i; }
        else if (i < SEG2) { sp = p1; off = i - SEG1; }
        else if (i < SEG3) { sp = p2; off = i - SEG2; }
        else if (i < SEG4) { sp = p3; off = i - SEG3; }
        else if (i < SEG5) { sp = p4; off = i - SEG4; }
        else if (i < SEG6) { sp = p5; off = i - SEG5; }
        else if (i < SEG7) { sp = p6; off = i - SEG6; }
        else if (i < SEG8) { sp = p7; off = i - SEG7; }
        else if (i < SEG9) { sp = p8; off = i - SEG8; }
        else               { sp = p9; off = i - SEG9; }
        dst[i] = f ? f2bf(((const float*)sp)[off]) : ((const ushort*)sp)[off];
    }
}

// ---- rope table: tab[p*32+j] = (cos, sin) of (S-1-p)*theta_j ----
__global__ __launch_bounds__(256) void rope_tab_k(float2* __restrict__ tab) {
    int idx = blockIdx.x * 256 + threadIdx.x;   // 131072 entries
    int p = idx >> 5, j = idx & 31;
    float theta = exp2f(-(float)j * L2B_OVER_K);
    float ang = (float)(Sn - 1 - p) * theta;
    float s, c;
    sincosf(ang, &s, &c);
    tab[idx] = make_float2(c, s);
}

// ---- 512x512 bf16 transpose: Wt[dout][din] = W[din][dout] ----
__global__ __launch_bounds__(256) void transpose_k(const ushort* __restrict__ W, ushort* __restrict__ Wt) {
    __shared__ ushort t[64][65];
    int tid = threadIdx.x;
    int c = tid & 63, r0 = (tid >> 6) * 16;
    int bx = blockIdx.x * 64, by = blockIdx.y * 64;
    #pragma unroll
    for (int i = 0; i < 16; ++i) t[r0 + i][c] = W[(size_t)(by + r0 + i) * Dn + bx + c];
    __syncthreads();
    #pragma unroll
    for (int i = 0; i < 16; ++i) Wt[(size_t)(bx + r0 + i) * Dn + by + c] = t[c][r0 + i];
}

// ---- prep: Wr_t[h*64+ro][d] = SCALE * sum_e W[d][h*64+e] * RP[ro][h*64+e] ----
__global__ __launch_bounds__(256)
void prep_wr_k(const ushort* __restrict__ Wq, const ushort* __restrict__ Wk,
               const ushort* __restrict__ RPc, ushort* __restrict__ Wqr,
               ushort* __restrict__ Wkr) {
    __shared__ ushort As[64][72];   // RP slice [ro][e]
    __shared__ ushort Bs[64][72];   // W rows [d][e]
    const int tid = threadIdx.x;
    const int h = blockIdx.y, d0 = blockIdx.x * 64;
    const ushort* W = blockIdx.z ? Wk : Wq;
    ushort* Out = blockIdx.z ? Wkr : Wqr;
    #pragma unroll
    for (int j = 0; j < 2; ++j) {
        int lin = j * 256 + tid, row = lin >> 3, c = (lin & 7) * 8;
        *(uint4*)&As[row][c] = *(const uint4*)&RPc[(size_t)row * Dn + h * En + c];
        *(uint4*)&Bs[row][c] = *(const uint4*)&W[(size_t)(d0 + row) * Dn + h * En + c];
    }
    __syncthreads();
    const int w = tid >> 6, l = tid & 63;
    const int mt = (w >> 1) * 32, nt = (w & 1) * 32, lr = l & 15, lq = l >> 4;
    floatx4 acc[2][2] = {};
    #pragma unroll
    for (int ks = 0; ks < 64; ks += 32) {
        bf16x8 a0 = ldsfrag(&As[mt + lr][ks + lq * 8]);
        bf16x8 a1 = ldsfrag(&As[mt + 16 + lr][ks + lq * 8]);
        bf16x8 b0 = ldsfrag(&Bs[nt + lr][ks + lq * 8]);
        bf16x8 b1 = ldsfrag(&Bs[nt + 16 + lr][ks + lq * 8]);
        acc[0][0] = MFMA(a0, b0, acc[0][0]);
        acc[0][1] = MFMA(a0, b1, acc[0][1]);
        acc[1][0] = MFMA(a1, b0, acc[1][0]);
        acc[1][1] = MFMA(a1, b1, acc[1][1]);
    }
    #pragma unroll
    for (int mi = 0; mi < 2; ++mi)
        #pragma unroll
        for (int ni = 0; ni < 2; ++ni)
            #pragma unroll
            for (int ri = 0; ri < 4; ++ri) {
                int ro = mt + mi * 16 + lq * 4 + ri;
                int d = d0 + nt + ni * 16 + lr;
                Out[(size_t)(h * En + ro) * Dn + d] = f2bf(acc[mi][ni][ri] * SCALE);
            }
}

// ---- bias vector for fused GEMM: [bskip | bz | qb] (qb = SCALE * bq . r) ----
__global__ __launch_bounds__(512)
void prep_bias_k(const ushort* __restrict__ bskc, const ushort* __restrict__ bzc,
                 const ushort* __restrict__ bqc, const ushort* __restrict__ RPc,
                 float* __restrict__ biascat) {
    int i = threadIdx.x;
    biascat[i]       = bf2f(bskc[i]);
    biascat[512 + i] = bf2f(bzc[i]);
    int h = i >> 6, ro = i & 63;
    float s = 0.f;
    for (int e = 0; e < 64; ++e)
        s += bf2f(bqc[h * En + e]) * bf2f(RPc[(size_t)ro * Dn + h * En + e]);
    biascat[1024 + i] = s * SCALE;
}

// ---- fused projection GEMM: M=16384 N=1536(skip|z|qs) K=512, 128x128 tiles ----
// XOR-swizzled staging: LDS slot s (16B units) holds global chunk
// c = ((s&7) - (row>>1)) & 7 of row s>>3. Wave's 8 lanes cover one full 128B
// row -> 8x128B coalesced segments. ds_read: slot = row*8 + ((cc+(row>>1))&7),
// banks spread 8-wide x 2 lanes = conflict-free.
__global__ __launch_bounds__(256)
void gemm_fused_k(const ushort* __restrict__ X, const ushort* __restrict__ Wtcat,
                  const float* __restrict__ biascat, ushort* __restrict__ skip,
                  ushort* __restrict__ z, ushort* __restrict__ qs) {
    __shared__ __align__(16) ushort As[8192];   // 128 rows x 64 k (swizzled)
    __shared__ __align__(16) ushort Bs[8192];
    const int tid = threadIdx.x;
    const int w = tid >> 6, l = tid & 63;
    const int n0 = blockIdx.x * 128;
    const int m0 = blockIdx.y * 128;
    const int mt = (w >> 1) * 64, nt = (w & 1) * 64;
    const int lr = l & 15, lq = l >> 4;
    floatx4 acc[4][4] = {};
    for (int kc = 0; kc < Dn; kc += 64) {
        __syncthreads();
        #pragma unroll
        for (int j = 0; j < 4; ++j) {
            int slot = (w * 4 + j) * 64 + l;            // lane's LDS slot (16B)
            int row = slot >> 3;
            int c = ((slot & 7) - (row >> 1)) & 7;      // swizzled global chunk
            gload16(&X[(size_t)(m0 + row) * Dn + kc + c * 8], &As[(w * 4 + j) * 512]);
            gload16(&Wtcat[(size_t)(n0 + row) * Dn + kc + c * 8], &Bs[(w * 4 + j) * 512]);
        }
        __syncthreads();
        #pragma unroll
        for (int ks = 0; ks < 64; ks += 32) {
            bf16x8 a[4], bb[4];
            const int cc = (ks >> 3) + lq;
            #pragma unroll
            for (int i = 0; i < 4; ++i) {
                int row = mt + 16 * i + lr;
                a[i] = ldsfrag(&As[(row * 8 + ((cc + (row >> 1)) & 7)) * 8]);
            }
            #pragma unroll
            for (int i = 0; i < 4; ++i) {
                int row = nt + 16 * i + lr;
                bb[i] = ldsfrag(&Bs[(row * 8 + ((cc + (row >> 1)) & 7)) * 8]);
            }
            #pragma unroll
            for (int mi = 0; mi < 4; ++mi)
                #pragma unroll
                for (int ni = 0; ni < 4; ++ni)
                    acc[mi][ni] = MFMA(a[mi], bb[ni], acc[mi][ni]);
        }
    }
    const int sec = n0 >> 9;                    // 0=skip 1=z 2=qs
    ushort* dst = sec == 0 ? skip : (sec == 1 ? z : qs);
    #pragma unroll
    for (int ni = 0; ni < 4; ++ni) {
        int ng = n0 + nt + ni * 16 + lr;
        float bbv = biascat[ng];
        int nc = ng & 511;
        #pragma unroll
        for (int mi = 0; mi < 4; ++mi)
            #pragma unroll
            for (int ri = 0; ri < 4; ++ri) {
                int row = m0 + mt + mi * 16 + lq * 4 + ri;
                float v = acc[mi][ni][ri] + bbv;
                if (sec == 1) v = v / (1.0f + __expf(-v));
                dst[(size_t)row * Dn + nc] = f2bf(v);
            }
    }
}

// ---- router scores + exp + row-sum: E[(bh,r)][s] = exp(Wkr[h,r,:].x[b,s,:]),
//      lsum[(bh,r)] += sum_s E. Safe without max-subtract (scores ~N(0,1)). ----
__global__ __launch_bounds__(256)
void rscore_k(const ushort* __restrict__ Wkr, const ushort* __restrict__ X,
              ushort* __restrict__ E, float* __restrict__ lsum) {
    __shared__ __align__(16) ushort Xs[64][520];  // [s][d] padded
    __shared__ __align__(16) ushort As[64][72];   // Wkr slice [r][64]
    const int tid = threadIdx.x;
    const int b = blockIdx.y, s0 = blockIdx.x * 64;
    #pragma unroll
    for (int i = 0; i < 16; ++i) {
        int lin = i * 256 + tid;
        int row = lin >> 6, c = (lin & 63) * 8;
        *(uint4*)&Xs[row][c] = *(const uint4*)&X[(size_t)(b * Ln + s0 + row) * Dn + c];
    }
    const int w = tid >> 6, l = tid & 63;
    const int mt = (w >> 1) * 32, nt = (w & 1) * 32, lr = l & 15, lq = l >> 4;
    for (int h = 0; h < Hn; ++h) {
        floatx4 acc[2][2] = {};
        for (int kc = 0; kc < Dn; kc += 64) {
            __syncthreads();
            #pragma unroll
            for (int j = 0; j < 2; ++j) {
                int lin = j * 256 + tid, row = lin >> 3, c = (lin & 7) * 8;
                *(uint4*)&As[row][c] = *(const uint4*)&Wkr[(size_t)(h * En + row) * Dn + kc + c];
            }
            __syncthreads();
            #pragma unroll
            for (int ks = 0; ks < 64; ks += 32) {
                bf16x8 a0 = ldsfrag(&As[mt + lr][ks + lq * 8]);
                bf16x8 a1 = ldsfrag(&As[mt + 16 + lr][ks + lq * 8]);
                bf16x8 b0 = ldsfrag(&Xs[nt + lr][kc + ks + lq * 8]);
                bf16x8 b1 = ldsfrag(&Xs[nt + 16 + lr][kc + ks + lq * 8]);
                acc[0][0] = MFMA(a0, b0, acc[0][0]);
                acc[0][1] = MFMA(a0, b1, acc[0][1]);
                acc[1][0] = MFMA(a1, b0, acc[1][0]);
                acc[1][1] = MFMA(a1, b1, acc[1][1]);
            }
        }
        const size_t rbase = (size_t)(b * Hn + h) * Rn;
        #pragma unroll
        for (int mi = 0; mi < 2; ++mi)
            #pragma unroll
            for (int ri = 0; ri < 4; ++ri) {
                int r = mt + mi * 16 + lq * 4 + ri;
                float rs = 0.f;
                #pragma unroll
                for (int ni = 0; ni < 2; ++ni) {
                    int s = s0 + nt + ni * 16 + lr;
                    float e = __expf(acc[mi][ni][ri]);
                    E[(rbase + r) * Sn + s] = f2bf(e);
                    rs += e;
                }
                rs += __shfl_xor(rs, 1); rs += __shfl_xor(rs, 2);
                rs += __shfl_xor(rs, 4); rs += __shfl_xor(rs, 8);
                if (lr == 0) atomicAdd(&lsum[rbase + r], rs);
            }
    }
}

// ---- rV[bh][r][e] += sum_s rope(E/l)[r][s] * v[s][e] ----
__global__ __launch_bounds__(256)
void router_v_k(const ushort* __restrict__ E, const float* __restrict__ lsum,
                const ushort* __restrict__ X, const float2* __restrict__ tab,
                float* __restrict__ rV) {
    __shared__ ushort As[64][72];
    __shared__ ushort Bs[64][72];
    __shared__ float invl[64];
    const int tid = threadIdx.x;
    const int bh = blockIdx.y, b = bh >> 3, h = bh & 7;
    const int w = tid >> 6, l = tid & 63;
    const int mt = (w >> 1) * 32, nt = (w & 1) * 32, lr = l & 15, lq = l >> 4;
    if (tid < 64) invl[tid] = 1.0f / lsum[(size_t)bh * Rn + tid];
    floatx4 acc[2][2] = {};
    for (int t4 = 0; t4 < 4; ++t4) {
        const int sb = blockIdx.x * 256 + t4 * 64;
        __syncthreads();
        #pragma unroll
        for (int i = 0; i < 8; ++i) {
            int lin = i * 256 + tid;
            int j = lin >> 6, sl = lin & 63;
            int sg2 = sb + sl;
            float pe = bf2f(E[((size_t)bh * Rn + 2 * j) * Sn + sg2]) * invl[2 * j];
            float po = bf2f(E[((size_t)bh * Rn + 2 * j + 1) * Sn + sg2]) * invl[2 * j + 1];
            float2 cs = tab[sg2 * 32 + j];
            As[2 * j][sl]     = f2bf(pe * cs.x - po * cs.y);
            As[2 * j + 1][sl] = f2bf(pe * cs.y + po * cs.x);
        }
        #pragma unroll
        for (int i = 0; i < 16; ++i) {
            int lin = i * 256 + tid;
            int sl = lin >> 6, e = lin & 63;
            Bs[e][sl] = X[(size_t)(b * Ln + sb + sl) * Dn + h * En + e];
        }
        __syncthreads();
        #pragma unroll
        for (int ks = 0; ks < 64; ks += 32) {
            bf16x8 a0 = ldsfrag(&As[mt + lr][ks + lq * 8]);
            bf16x8 a1 = ldsfrag(&As[mt + 16 + lr][ks + lq * 8]);
            bf16x8 b0 = ldsfrag(&Bs[nt + lr][ks + lq * 8]);
            bf16x8 b1 = ldsfrag(&Bs[nt + 16 + lr][ks + lq * 8]);
            acc[0][0] = MFMA(a0, b0, acc[0][0]);
            acc[0][1] = MFMA(a0, b1, acc[0][1]);
            acc[1][0] = MFMA(a1, b0, acc[1][0]);
            acc[1][1] = MFMA(a1, b1, acc[1][1]);
        }
    }
    #pragma unroll
    for (int mi = 0; mi < 2; ++mi)
        #pragma unroll
        for (int ni = 0; ni < 2; ++ni)
            #pragma unroll
            for (int ri = 0; ri < 4; ++ri) {
                int r = mt + mi * 16 + lq * 4 + ri;
                int e = nt + ni * 16 + lr;
                atomicAdd(&rV[((size_t)bh * Rn + r) * En + e], acc[mi][ni][ri]);
            }
}

// ---- fused query path: qs -> in-thread softmax -> rope -> @rV -> (+skip)*z ----
__global__ __launch_bounds__(256)
void final_attn_k(const ushort* __restrict__ QS, const float* __restrict__ rV,
                  const float2* __restrict__ tab, const ushort* __restrict__ Skip,
                  const ushort* __restrict__ Zs, const int* __restrict__ flagp,
                  void* __restrict__ Outv) {
    __shared__ ushort Ap[64][72];
    __shared__ ushort BvT[64][72];
    const int f = *flagp;
    const int tid = threadIdx.x;
    const int h = blockIdx.y, b = blockIdx.z, bh = b * Hn + h;
    const int l0 = blockIdx.x * 64;
    const int w = tid >> 6, l = tid & 63;
    const int mt = (w >> 1) * 32, nt = (w & 1) * 32, lr = l & 15, lq = l >> 4;
    #pragma unroll
    for (int i = 0; i < 16; ++i) {
        int lin = i * 256 + tid, r = lin >> 6, e = lin & 63;
        BvT[e][r] = f2bf(rV[((size_t)bh * Rn + r) * En + e]);
    }
    {   // quad-per-token softmax + rope: thread = (token lt, quarter qd)
        const int lt = tid >> 2, qd = tid & 3;
        const ushort* qrow = &QS[(size_t)(b * Ln + l0 + lt) * Dn + h * En + qd * 16];
        uint4 u0 = ((const uint4*)qrow)[0];
        uint4 u1 = ((const uint4*)qrow)[1];
        uint uw[8] = {u0.x, u0.y, u0.z, u0.w, u1.x, u1.y, u1.z, u1.w};
        float p[16];
        float s = 0.f;
        #pragma unroll
        for (int j = 0; j < 8; ++j) {
            float flo = __uint_as_float(uw[j] << 16);
            float fhi = __uint_as_float(uw[j] & 0xffff0000u);
            float e0 = __expf(flo), e1 = __expf(fhi);
            p[2 * j] = e0; p[2 * j + 1] = e1;
            s += e0 + e1;
        }
        s += __shfl_xor(s, 1);
        s += __shfl_xor(s, 2);
        float inv = 1.0f / s;
        #pragma unroll
        for (int u = 0; u < 8; ++u) {
            float A0 = p[2 * u] * inv, A1 = p[2 * u + 1] * inv;
            float2 cs = tab[(l0 + lt) * 32 + qd * 8 + u];
            Ap[lt][qd * 16 + 2 * u]     = f2bf(A0 * cs.x - A1 * cs.y);
            Ap[lt][qd * 16 + 2 * u + 1] = f2bf(A0 * cs.y + A1 * cs.x);
        }
    }
    __syncthreads();
    floatx4 acc[2][2] = {};
    #pragma unroll
    for (int ks = 0; ks < 64; ks += 32) {
        bf16x8 a0 = ldsfrag(&Ap[mt + lr][ks + lq * 8]);
        bf16x8 a1 = ldsfrag(&Ap[mt + 16 + lr][ks + lq * 8]);
        bf16x8 b0 = ldsfrag(&BvT[nt + lr][ks + lq * 8]);
        bf16x8 b1 = ldsfrag(&BvT[nt + 16 + lr][ks + lq * 8]);
        acc[0][0] = MFMA(a0, b0, acc[0][0]);
        acc[0][1] = MFMA(a0, b1, acc[0][1]);
        acc[1][0] = MFMA(a1, b0, acc[1][0]);
        acc[1][1] = MFMA(a1, b1, acc[1][1]);
    }
    #pragma unroll
    for (int mi = 0; mi < 2; ++mi)
        #pragma unroll
        for (int ni = 0; ni < 2; ++ni)
            #pragma unroll
            for (int ri = 0; ri < 4; ++ri) {
                int row = mt + mi * 16 + lq * 4 + ri;
                int e = nt + ni * 16 + lr;
                size_t idx = (size_t)(b * Ln + l0 + row) * Dn + h * En + e;
                float v = acc[mi][ni][ri];
                float val = (v + bf2f(Skip[idx])) * bf2f(Zs[idx]);
                if (f) ((float*)Outv)[idx] = val;
                else   ((ushort*)Outv)[idx] = f2bf(val);
            }
}

extern "C" void kernel_launch(void* const* d_in, const int* in_sizes, int n_in,
                              void* d_out, int out_size, void* d_ws, size_t ws_size,
                              hipStream_t stream) {
    const size_t OFF_SK    = 0;                  // 16 MiB bf16 [16384][512]
    const size_t OFF_Z     = 16777216;
    const size_t OFF_QS    = 33554432;
    const size_t OFF_E     = 50331648;           // 16 MiB bf16 E
    const size_t OFF_RV    = 67108864;           // 512 KiB f32
    const size_t OFF_L     = 67633152;           // 8 KiB f32 lsum
    const size_t OFF_TAB   = 67641344;           // 1 MiB
    const size_t OFF_WT    = 68689920;           // Wtcat 1536x512 bf16 = 1.5 MiB
    const size_t OFF_WKR   = 70262784;           // 512x512 bf16
    const size_t OFF_BIAS  = 70787072;           // 1536 f32
    const size_t OFF_CANON = 70793216;           // 18,944,000 B
    const size_t OFF_FLAG  = OFF_CANON + 18944000;
    const size_t NEED      = OFF_FLAG + 16;      // ~89.8 MB
    if (ws_size < NEED) return;

    char* ws = (char*)d_ws;
    ushort* skip  = (ushort*)(ws + OFF_SK);
    ushort* z     = (ushort*)(ws + OFF_Z);
    ushort* qs    = (ushort*)(ws + OFF_QS);
    ushort* E     = (ushort*)(ws + OFF_E);
    float*  rV    = (float*)(ws + OFF_RV);
    float*  lsum  = (float*)(ws + OFF_L);
    float2* tab   = (float2*)(ws + OFF_TAB);
    ushort* Wtcat = (ushort*)(ws + OFF_WT);
    ushort* Wkr   = (ushort*)(ws + OFF_WKR);
    float*  bias  = (float*)(ws + OFF_BIAS);
    ushort* canon = (ushort*)(ws + OFF_CANON);
    int*    flag  = (int*)(ws + OFF_FLAG);

    const ushort* Xc   = canon;
    const ushort* Wqc  = canon + SEG1;
    const ushort* bqc  = canon + SEG2;
    const ushort* Wkc  = canon + SEG3;
    const ushort* Wskc = canon + SEG5;
    const ushort* bskc = canon + SEG6;
    const ushort* Wzc  = canon + SEG7;
    const ushort* bzc  = canon + SEG8;
    const ushort* RPc  = canon + SEG9;

    sniff_k<<<1, 256, 0, stream>>>((const uint*)d_in[0], flag);
    canon_k<<<9250, 256, 0, stream>>>(d_in[0], d_in[1], d_in[2], d_in[3], d_in[4],
                                      d_in[5], d_in[6], d_in[7], d_in[8], d_in[9],
                                      flag, canon);
    hipMemsetAsync(rV, 0, 524288, stream);
    hipMemsetAsync(lsum, 0, 8192, stream);
    rope_tab_k<<<512, 256, 0, stream>>>(tab);
    dim3 tg(8, 8);
    transpose_k<<<tg, 256, 0, stream>>>(Wskc, Wtcat);            // sec0 = Wskip^T
    transpose_k<<<tg, 256, 0, stream>>>(Wzc,  Wtcat + 262144);   // sec1 = Wz^T
    prep_wr_k<<<dim3(8, 8, 2), 256, 0, stream>>>(Wqc, Wkc, RPc,
                                                 Wtcat + 524288, Wkr); // sec2 = Wqr
    prep_bias_k<<<1, 512, 0, stream>>>(bskc, bzc, bqc, RPc, bias);
    gemm_fused_k<<<dim3(12, 128), 256, 0, stream>>>(Xc, Wtcat, bias, skip, z, qs);
    rscore_k<<<dim3(64, 4), 256, 0, stream>>>(Wkr, Xc, E, lsum);
    router_v_k<<<dim3(16, 32), 256, 0, stream>>>(E, lsum, Xc, tab, rV);
    final_attn_k<<<dim3(64, 8, 4), 256, 0, stream>>>(qs, rV, tab, skip, z, flag, d_out);
}

// Round 5
// 243.911 us; speedup vs baseline: 1.3440x; 1.3440x over previous
//
#include <hip/hip_runtime.h>

// RouterAttention on gfx950. B=4 L=S=4096 D=512 H=8 E=R=64.
// R5: rscore rebuilt as a 128x128-tile MFMA GEMM (M=512=(h,r), N=16384=(b,s),
// K=512) — same structure as gemm_fused_k (512 blocks, 32KB LDS, swizzled
// global_load_lds staging) with exp + E-store + row-sum epilogue. Replaces the
// 256-block latency-bound R4 rscore (104.9us, 3% everything).

#define DEV __device__ __forceinline__

constexpr int Bn = 4, Ln = 4096, Dn = 512, Hn = 8, En = 64, Rn = 64;
constexpr int Sn = 4096;
constexpr float SCALE = 0.125f;                 // 1/sqrt(E)
constexpr float L2B_OVER_K = 13.287712379549449f / 32.0f; // log2(10000)/32

typedef __bf16 bf16x8 __attribute__((ext_vector_type(8)));
typedef float floatx4 __attribute__((ext_vector_type(4)));

DEV float bf2f(ushort u) { return __uint_as_float(((unsigned)u) << 16); }
DEV ushort f2bf(float f) {
    unsigned u = __float_as_uint(f);
    u += 0x7fffu + ((u >> 16) & 1u);            // RNE
    return (ushort)(u >> 16);
}
DEV bf16x8 ldsfrag(const ushort* p) { return *reinterpret_cast<const bf16x8*>(p); }
#define MFMA(a, b, c) __builtin_amdgcn_mfma_f32_16x16x32_bf16(a, b, c, 0, 0, 0)

DEV void gload16(const ushort* g, ushort* lds) {
    __builtin_amdgcn_global_load_lds(
        (const __attribute__((address_space(1))) unsigned int*)g,
        (__attribute__((address_space(3))) unsigned int*)lds, 16, 0, 0);
}

DEV int wave_sum_i(int v) {
    #pragma unroll
    for (int off = 1; off < 64; off <<= 1) v += __shfl_xor(v, off);
    return v;
}

// ---- dtype sniffer: flag=1 if x looks like f32, 0 if bf16-packed ----
__global__ __launch_bounds__(256) void sniff_k(const uint* __restrict__ x, int* __restrict__ flag) {
    int t = threadIdx.x, cnt = 0;
    #pragma unroll
    for (int i = 0; i < 16; ++i) {
        uint u = x[t * 16 + i];
        uint e = (u >> 7) & 0xFF;
        cnt += (e >= 100 && e <= 140) ? 1 : 0;
    }
    cnt = wave_sum_i(cnt);
    __shared__ int red[4];
    int w = t >> 6, l = t & 63;
    if (l == 0) red[w] = cnt;
    __syncthreads();
    if (t == 0) flag[0] = ((red[0] + red[1] + red[2] + red[3]) < 2048) ? 1 : 0;
}

// ---- canonicalize all 10 inputs into contiguous bf16 region ----
constexpr size_t SEG1 = 8388608, SEG2 = 8650752, SEG3 = 8651264, SEG4 = 8913408,
                 SEG5 = 8913920, SEG6 = 9176064, SEG7 = 9176576, SEG8 = 9438720,
                 SEG9 = 9439232, SEGT = 9472000;
__global__ __launch_bounds__(256)
void canon_k(const void* p0, const void* p1, const void* p2, const void* p3,
             const void* p4, const void* p5, const void* p6, const void* p7,
             const void* p8, const void* p9, const int* __restrict__ flag,
             ushort* __restrict__ dst) {
    const int f = *flag;
    size_t i0 = (size_t)blockIdx.x * 1024 + threadIdx.x;
    #pragma unroll
    for (int r = 0; r < 4; ++r) {
        size_t i = i0 + (size_t)r * 256;
        if (i >= SEGT) return;
        const void* sp; size_t off;
        if      (i < SEG1) { sp = p0; off = i; }
        else if (i < SEG2) { sp = p1; off = i - SEG1; }
        else if (i < SEG3) { sp = p2; off = i - SEG2; }
        else if (i < SEG4) { sp = p3; off = i - SEG3; }
        else if (i < SEG5) { sp = p4; off = i - SEG4; }
        else if (i < SEG6) { sp = p5; off = i - SEG5; }
        else if (i < SEG7) { sp = p6; off = i - SEG6; }
        else if (i < SEG8) { sp = p7; off = i - SEG7; }
        else if (i < SEG9) { sp = p8; off = i - SEG8; }
        else               { sp = p9; off = i - SEG9; }
        dst[i] = f ? f2bf(((const float*)sp)[off]) : ((const ushort*)sp)[off];
    }
}

// ---- rope table: tab[p*32+j] = (cos, sin) of (S-1-p)*theta_j ----
__global__ __launch_bounds__(256) void rope_tab_k(float2* __restrict__ tab) {
    int idx = blockIdx.x * 256 + threadIdx.x;   // 131072 entries
    int p = idx >> 5, j = idx & 31;
    float theta = exp2f(-(float)j * L2B_OVER_K);
    float ang = (float)(Sn - 1 - p) * theta;
    float s, c;
    sincosf(ang, &s, &c);
    tab[idx] = make_float2(c, s);
}

// ---- 512x512 bf16 transpose: Wt[dout][din] = W[din][dout] ----
__global__ __launch_bounds__(256) void transpose_k(const ushort* __restrict__ W, ushort* __restrict__ Wt) {
    __shared__ ushort t[64][65];
    int tid = threadIdx.x;
    int c = tid & 63, r0 = (tid >> 6) * 16;
    int bx = blockIdx.x * 64, by = blockIdx.y * 64;
    #pragma unroll
    for (int i = 0; i < 16; ++i) t[r0 + i][c] = W[(size_t)(by + r0 + i) * Dn + bx + c];
    __syncthreads();
    #pragma unroll
    for (int i = 0; i < 16; ++i) Wt[(size_t)(bx + r0 + i) * Dn + by + c] = t[c][r0 + i];
}

// ---- prep: Wr_t[h*64+ro][d] = SCALE * sum_e W[d][h*64+e] * RP[ro][h*64+e] ----
__global__ __launch_bounds__(256)
void prep_wr_k(const ushort* __restrict__ Wq, const ushort* __restrict__ Wk,
               const ushort* __restrict__ RPc, ushort* __restrict__ Wqr,
               ushort* __restrict__ Wkr) {
    __shared__ ushort As[64][72];   // RP slice [ro][e]
    __shared__ ushort Bs[64][72];   // W rows [d][e]
    const int tid = threadIdx.x;
    const int h = blockIdx.y, d0 = blockIdx.x * 64;
    const ushort* W = blockIdx.z ? Wk : Wq;
    ushort* Out = blockIdx.z ? Wkr : Wqr;
    #pragma unroll
    for (int j = 0; j < 2; ++j) {
        int lin = j * 256 + tid, row = lin >> 3, c = (lin & 7) * 8;
        *(uint4*)&As[row][c] = *(const uint4*)&RPc[(size_t)row * Dn + h * En + c];
        *(uint4*)&Bs[row][c] = *(const uint4*)&W[(size_t)(d0 + row) * Dn + h * En + c];
    }
    __syncthreads();
    const int w = tid >> 6, l = tid & 63;
    const int mt = (w >> 1) * 32, nt = (w & 1) * 32, lr = l & 15, lq = l >> 4;
    floatx4 acc[2][2] = {};
    #pragma unroll
    for (int ks = 0; ks < 64; ks += 32) {
        bf16x8 a0 = ldsfrag(&As[mt + lr][ks + lq * 8]);
        bf16x8 a1 = ldsfrag(&As[mt + 16 + lr][ks + lq * 8]);
        bf16x8 b0 = ldsfrag(&Bs[nt + lr][ks + lq * 8]);
        bf16x8 b1 = ldsfrag(&Bs[nt + 16 + lr][ks + lq * 8]);
        acc[0][0] = MFMA(a0, b0, acc[0][0]);
        acc[0][1] = MFMA(a0, b1, acc[0][1]);
        acc[1][0] = MFMA(a1, b0, acc[1][0]);
        acc[1][1] = MFMA(a1, b1, acc[1][1]);
    }
    #pragma unroll
    for (int mi = 0; mi < 2; ++mi)
        #pragma unroll
        for (int ni = 0; ni < 2; ++ni)
            #pragma unroll
            for (int ri = 0; ri < 4; ++ri) {
                int ro = mt + mi * 16 + lq * 4 + ri;
                int d = d0 + nt + ni * 16 + lr;
                Out[(size_t)(h * En + ro) * Dn + d] = f2bf(acc[mi][ni][ri] * SCALE);
            }
}

// ---- bias vector for fused GEMM: [bskip | bz | qb] (qb = SCALE * bq . r) ----
__global__ __launch_bounds__(512)
void prep_bias_k(const ushort* __restrict__ bskc, const ushort* __restrict__ bzc,
                 const ushort* __restrict__ bqc, const ushort* __restrict__ RPc,
                 float* __restrict__ biascat) {
    int i = threadIdx.x;
    biascat[i]       = bf2f(bskc[i]);
    biascat[512 + i] = bf2f(bzc[i]);
    int h = i >> 6, ro = i & 63;
    float s = 0.f;
    for (int e = 0; e < 64; ++e)
        s += bf2f(bqc[h * En + e]) * bf2f(RPc[(size_t)ro * Dn + h * En + e]);
    biascat[1024 + i] = s * SCALE;
}

// ---- fused projection GEMM: M=16384 N=1536(skip|z|qs) K=512, 128x128 tiles ----
__global__ __launch_bounds__(256)
void gemm_fused_k(const ushort* __restrict__ X, const ushort* __restrict__ Wtcat,
                  const float* __restrict__ biascat, ushort* __restrict__ skip,
                  ushort* __restrict__ z, ushort* __restrict__ qs) {
    __shared__ __align__(16) ushort As[8192];   // 128 rows x 64 k (swizzled)
    __shared__ __align__(16) ushort Bs[8192];
    const int tid = threadIdx.x;
    const int w = tid >> 6, l = tid & 63;
    const int n0 = blockIdx.x * 128;
    const int m0 = blockIdx.y * 128;
    const int mt = (w >> 1) * 64, nt = (w & 1) * 64;
    const int lr = l & 15, lq = l >> 4;
    floatx4 acc[4][4] = {};
    for (int kc = 0; kc < Dn; kc += 64) {
        __syncthreads();
        #pragma unroll
        for (int j = 0; j < 4; ++j) {
            int slot = (w * 4 + j) * 64 + l;            // lane's LDS slot (16B)
            int row = slot >> 3;
            int c = ((slot & 7) - (row >> 1)) & 7;      // swizzled global chunk
            gload16(&X[(size_t)(m0 + row) * Dn + kc + c * 8], &As[(w * 4 + j) * 512]);
            gload16(&Wtcat[(size_t)(n0 + row) * Dn + kc + c * 8], &Bs[(w * 4 + j) * 512]);
        }
        __syncthreads();
        #pragma unroll
        for (int ks = 0; ks < 64; ks += 32) {
            bf16x8 a[4], bb[4];
            const int cc = (ks >> 3) + lq;
            #pragma unroll
            for (int i = 0; i < 4; ++i) {
                int row = mt + 16 * i + lr;
                a[i] = ldsfrag(&As[(row * 8 + ((cc + (row >> 1)) & 7)) * 8]);
            }
            #pragma unroll
            for (int i = 0; i < 4; ++i) {
                int row = nt + 16 * i + lr;
                bb[i] = ldsfrag(&Bs[(row * 8 + ((cc + (row >> 1)) & 7)) * 8]);
            }
            #pragma unroll
            for (int mi = 0; mi < 4; ++mi)
                #pragma unroll
                for (int ni = 0; ni < 4; ++ni)
                    acc[mi][ni] = MFMA(a[mi], bb[ni], acc[mi][ni]);
        }
    }
    const int sec = n0 >> 9;                    // 0=skip 1=z 2=qs
    ushort* dst = sec == 0 ? skip : (sec == 1 ? z : qs);
    #pragma unroll
    for (int ni = 0; ni < 4; ++ni) {
        int ng = n0 + nt + ni * 16 + lr;
        float bbv = biascat[ng];
        int nc = ng & 511;
        #pragma unroll
        for (int mi = 0; mi < 4; ++mi)
            #pragma unroll
            for (int ri = 0; ri < 4; ++ri) {
                int row = m0 + mt + mi * 16 + lq * 4 + ri;
                float v = acc[mi][ni][ri] + bbv;
                if (sec == 1) v = v / (1.0f + __expf(-v));
                dst[(size_t)row * Dn + nc] = f2bf(v);
            }
    }
}

// ---- router scores as GEMM: M=512=(h*64+r) [Wkr rows], N=16384=(b,s) [x rows],
//      K=512. Epilogue: E[(b*512+m)][s] = exp(acc), lsum[b*512+m] += row sums.
//      Same 327-TF structure as gemm_fused_k; 512 blocks. ----
__global__ __launch_bounds__(256)
void rscore_gemm_k(const ushort* __restrict__ Wkr, const ushort* __restrict__ X,
                   ushort* __restrict__ E, float* __restrict__ lsum) {
    __shared__ __align__(16) ushort As[8192];   // Wkr tile (swizzled)
    __shared__ __align__(16) ushort Bs[8192];   // x tile
    const int tid = threadIdx.x;
    const int w = tid >> 6, l = tid & 63;
    const int n0 = blockIdx.x * 128;            // x row = b*4096 + s
    const int m0 = blockIdx.y * 128;            // Wkr row = h*64+r
    const int mt = (w >> 1) * 64, nt = (w & 1) * 64;
    const int lr = l & 15, lq = l >> 4;
    floatx4 acc[4][4] = {};
    for (int kc = 0; kc < Dn; kc += 64) {
        __syncthreads();
        #pragma unroll
        for (int j = 0; j < 4; ++j) {
            int slot = (w * 4 + j) * 64 + l;
            int row = slot >> 3;
            int c = ((slot & 7) - (row >> 1)) & 7;
            gload16(&Wkr[(size_t)(m0 + row) * Dn + kc + c * 8], &As[(w * 4 + j) * 512]);
            gload16(&X[(size_t)(n0 + row) * Dn + kc + c * 8], &Bs[(w * 4 + j) * 512]);
        }
        __syncthreads();
        #pragma unroll
        for (int ks = 0; ks < 64; ks += 32) {
            bf16x8 a[4], bb[4];
            const int cc = (ks >> 3) + lq;
            #pragma unroll
            for (int i = 0; i < 4; ++i) {
                int row = mt + 16 * i + lr;
                a[i] = ldsfrag(&As[(row * 8 + ((cc + (row >> 1)) & 7)) * 8]);
            }
            #pragma unroll
            for (int i = 0; i < 4; ++i) {
                int row = nt + 16 * i + lr;
                bb[i] = ldsfrag(&Bs[(row * 8 + ((cc + (row >> 1)) & 7)) * 8]);
            }
            #pragma unroll
            for (int mi = 0; mi < 4; ++mi)
                #pragma unroll
                for (int ni = 0; ni < 4; ++ni)
                    acc[mi][ni] = MFMA(a[mi], bb[ni], acc[mi][ni]);
        }
    }
    const int b = n0 >> 12;                     // batch index
    const int sbase = (n0 & 4095) + nt;
    #pragma unroll
    for (int mi = 0; mi < 4; ++mi)
        #pragma unroll
        for (int ri = 0; ri < 4; ++ri) {
            size_t row = (size_t)(b * 512 + m0 + mt + mi * 16 + lq * 4 + ri);
            float rs = 0.f;
            #pragma unroll
            for (int ni = 0; ni < 4; ++ni) {
                int s = sbase + ni * 16 + lr;
                float e = __expf(acc[mi][ni][ri]);
                E[row * Sn + s] = f2bf(e);
                rs += e;
            }
            rs += __shfl_xor(rs, 1); rs += __shfl_xor(rs, 2);
            rs += __shfl_xor(rs, 4); rs += __shfl_xor(rs, 8);
            if (lr == 0) atomicAdd(&lsum[row], rs);
        }
}

// ---- rV[bh][r][e] += sum_s rope(E/l)[r][s] * v[s][e] ----
__global__ __launch_bounds__(256)
void router_v_k(const ushort* __restrict__ E, const float* __restrict__ lsum,
                const ushort* __restrict__ X, const float2* __restrict__ tab,
                float* __restrict__ rV) {
    __shared__ ushort As[64][72];
    __shared__ ushort Bs[64][72];
    __shared__ float invl[64];
    const int tid = threadIdx.x;
    const int bh = blockIdx.y, b = bh >> 3, h = bh & 7;
    const int w = tid >> 6, l = tid & 63;
    const int mt = (w >> 1) * 32, nt = (w & 1) * 32, lr = l & 15, lq = l >> 4;
    if (tid < 64) invl[tid] = 1.0f / lsum[(size_t)bh * Rn + tid];
    floatx4 acc[2][2] = {};
    for (int t4 = 0; t4 < 4; ++t4) {
        const int sb = blockIdx.x * 256 + t4 * 64;
        __syncthreads();
        #pragma unroll
        for (int i = 0; i < 8; ++i) {
            int lin = i * 256 + tid;
            int j = lin >> 6, sl = lin & 63;
            int sg2 = sb + sl;
            float pe = bf2f(E[((size_t)bh * Rn + 2 * j) * Sn + sg2]) * invl[2 * j];
            float po = bf2f(E[((size_t)bh * Rn + 2 * j + 1) * Sn + sg2]) * invl[2 * j + 1];
            float2 cs = tab[sg2 * 32 + j];
            As[2 * j][sl]     = f2bf(pe * cs.x - po * cs.y);
            As[2 * j + 1][sl] = f2bf(pe * cs.y + po * cs.x);
        }
        #pragma unroll
        for (int i = 0; i < 16; ++i) {
            int lin = i * 256 + tid;
            int sl = lin >> 6, e = lin & 63;
            Bs[e][sl] = X[(size_t)(b * Ln + sb + sl) * Dn + h * En + e];
        }
        __syncthreads();
        #pragma unroll
        for (int ks = 0; ks < 64; ks += 32) {
            bf16x8 a0 = ldsfrag(&As[mt + lr][ks + lq * 8]);
            bf16x8 a1 = ldsfrag(&As[mt + 16 + lr][ks + lq * 8]);
            bf16x8 b0 = ldsfrag(&Bs[nt + lr][ks + lq * 8]);
            bf16x8 b1 = ldsfrag(&Bs[nt + 16 + lr][ks + lq * 8]);
            acc[0][0] = MFMA(a0, b0, acc[0][0]);
            acc[0][1] = MFMA(a0, b1, acc[0][1]);
            acc[1][0] = MFMA(a1, b0, acc[1][0]);
            acc[1][1] = MFMA(a1, b1, acc[1][1]);
        }
    }
    #pragma unroll
    for (int mi = 0; mi < 2; ++mi)
        #pragma unroll
        for (int ni = 0; ni < 2; ++ni)
            #pragma unroll
            for (int ri = 0; ri < 4; ++ri) {
                int r = mt + mi * 16 + lq * 4 + ri;
                int e = nt + ni * 16 + lr;
                atomicAdd(&rV[((size_t)bh * Rn + r) * En + e], acc[mi][ni][ri]);
            }
}

// ---- fused query path: qs -> in-thread softmax -> rope -> @rV -> (+skip)*z ----
__global__ __launch_bounds__(256)
void final_attn_k(const ushort* __restrict__ QS, const float* __restrict__ rV,
                  const float2* __restrict__ tab, const ushort* __restrict__ Skip,
                  const ushort* __restrict__ Zs, const int* __restrict__ flagp,
                  void* __restrict__ Outv) {
    __shared__ ushort Ap[64][72];
    __shared__ ushort BvT[64][72];
    const int f = *flagp;
    const int tid = threadIdx.x;
    const int h = blockIdx.y, b = blockIdx.z, bh = b * Hn + h;
    const int l0 = blockIdx.x * 64;
    const int w = tid >> 6, l = tid & 63;
    const int mt = (w >> 1) * 32, nt = (w & 1) * 32, lr = l & 15, lq = l >> 4;
    #pragma unroll
    for (int i = 0; i < 16; ++i) {
        int lin = i * 256 + tid, r = lin >> 6, e = lin & 63;
        BvT[e][r] = f2bf(rV[((size_t)bh * Rn + r) * En + e]);
    }
    {   // quad-per-token softmax + rope: thread = (token lt, quarter qd)
        const int lt = tid >> 2, qd = tid & 3;
        const ushort* qrow = &QS[(size_t)(b * Ln + l0 + lt) * Dn + h * En + qd * 16];
        uint4 u0 = ((const uint4*)qrow)[0];
        uint4 u1 = ((const uint4*)qrow)[1];
        uint uw[8] = {u0.x, u0.y, u0.z, u0.w, u1.x, u1.y, u1.z, u1.w};
        float p[16];
        float s = 0.f;
        #pragma unroll
        for (int j = 0; j < 8; ++j) {
            float flo = __uint_as_float(uw[j] << 16);
            float fhi = __uint_as_float(uw[j] & 0xffff0000u);
            float e0 = __expf(flo), e1 = __expf(fhi);
            p[2 * j] = e0; p[2 * j + 1] = e1;
            s += e0 + e1;
        }
        s += __shfl_xor(s, 1);
        s += __shfl_xor(s, 2);
        float inv = 1.0f / s;
        #pragma unroll
        for (int u = 0; u < 8; ++u) {
            float A0 = p[2 * u] * inv, A1 = p[2 * u + 1] * inv;
            float2 cs = tab[(l0 + lt) * 32 + qd * 8 + u];
            Ap[lt][qd * 16 + 2 * u]     = f2bf(A0 * cs.x - A1 * cs.y);
            Ap[lt][qd * 16 + 2 * u + 1] = f2bf(A0 * cs.y + A1 * cs.x);
        }
    }
    __syncthreads();
    floatx4 acc[2][2] = {};
    #pragma unroll
    for (int ks = 0; ks < 64; ks += 32) {
        bf16x8 a0 = ldsfrag(&Ap[mt + lr][ks + lq * 8]);
        bf16x8 a1 = ldsfrag(&Ap[mt + 16 + lr][ks + lq * 8]);
        bf16x8 b0 = ldsfrag(&BvT[nt + lr][ks + lq * 8]);
        bf16x8 b1 = ldsfrag(&BvT[nt + 16 + lr][ks + lq * 8]);
        acc[0][0] = MFMA(a0, b0, acc[0][0]);
        acc[0][1] = MFMA(a0, b1, acc[0][1]);
        acc[1][0] = MFMA(a1, b0, acc[1][0]);
        acc[1][1] = MFMA(a1, b1, acc[1][1]);
    }
    #pragma unroll
    for (int mi = 0; mi < 2; ++mi)
        #pragma unroll
        for (int ni = 0; ni < 2; ++ni)
            #pragma unroll
            for (int ri = 0; ri < 4; ++ri) {
                int row = mt + mi * 16 + lq * 4 + ri;
                int e = nt + ni * 16 + lr;
                size_t idx = (size_t)(b * Ln + l0 + row) * Dn + h * En + e;
                float v = acc[mi][ni][ri];
                float val = (v + bf2f(Skip[idx])) * bf2f(Zs[idx]);
                if (f) ((float*)Outv)[idx] = val;
                else   ((ushort*)Outv)[idx] = f2bf(val);
            }
}

extern "C" void kernel_launch(void* const* d_in, const int* in_sizes, int n_in,
                              void* d_out, int out_size, void* d_ws, size_t ws_size,
                              hipStream_t stream) {
    const size_t OFF_SK    = 0;                  // 16 MiB bf16 [16384][512]
    const size_t OFF_Z     = 16777216;
    const size_t OFF_QS    = 33554432;
    const size_t OFF_E     = 50331648;           // 16 MiB bf16 E
    const size_t OFF_RV    = 67108864;           // 512 KiB f32
    const size_t OFF_L     = 67633152;           // 8 KiB f32 lsum
    const size_t OFF_TAB   = 67641344;           // 1 MiB
    const size_t OFF_WT    = 68689920;           // Wtcat 1536x512 bf16 = 1.5 MiB
    const size_t OFF_WKR   = 70262784;           // 512x512 bf16
    const size_t OFF_BIAS  = 70787072;           // 1536 f32
    const size_t OFF_CANON = 70793216;           // 18,944,000 B
    const size_t OFF_FLAG  = OFF_CANON + 18944000;
    const size_t NEED      = OFF_FLAG + 16;      // ~89.8 MB
    if (ws_size < NEED) return;

    char* ws = (char*)d_ws;
    ushort* skip  = (ushort*)(ws + OFF_SK);
    ushort* z     = (ushort*)(ws + OFF_Z);
    ushort* qs    = (ushort*)(ws + OFF_QS);
    ushort* E     = (ushort*)(ws + OFF_E);
    float*  rV    = (float*)(ws + OFF_RV);
    float*  lsum  = (float*)(ws + OFF_L);
    float2* tab   = (float2*)(ws + OFF_TAB);
    ushort* Wtcat = (ushort*)(ws + OFF_WT);
    ushort* Wkr   = (ushort*)(ws + OFF_WKR);
    float*  bias  = (float*)(ws + OFF_BIAS);
    ushort* canon = (ushort*)(ws + OFF_CANON);
    int*    flag  = (int*)(ws + OFF_FLAG);

    const ushort* Xc   = canon;
    const ushort* Wqc  = canon + SEG1;
    const ushort* bqc  = canon + SEG2;
    const ushort* Wkc  = canon + SEG3;
    const ushort* Wskc = canon + SEG5;
    const ushort* bskc = canon + SEG6;
    const ushort* Wzc  = canon + SEG7;
    const ushort* bzc  = canon + SEG8;
    const ushort* RPc  = canon + SEG9;

    sniff_k<<<1, 256, 0, stream>>>((const uint*)d_in[0], flag);
    canon_k<<<9250, 256, 0, stream>>>(d_in[0], d_in[1], d_in[2], d_in[3], d_in[4],
                                      d_in[5], d_in[6], d_in[7], d_in[8], d_in[9],
                                      flag, canon);
    hipMemsetAsync(rV, 0, 524288, stream);
    hipMemsetAsync(lsum, 0, 8192, stream);
    rope_tab_k<<<512, 256, 0, stream>>>(tab);
    dim3 tg(8, 8);
    transpose_k<<<tg, 256, 0, stream>>>(Wskc, Wtcat);            // sec0 = Wskip^T
    transpose_k<<<tg, 256, 0, stream>>>(Wzc,  Wtcat + 262144);   // sec1 = Wz^T
    prep_wr_k<<<dim3(8, 8, 2), 256, 0, stream>>>(Wqc, Wkc, RPc,
                                                 Wtcat + 524288, Wkr); // sec2 = Wqr
    prep_bias_k<<<1, 512, 0, stream>>>(bskc, bzc, bqc, RPc, bias);
    gemm_fused_k<<<dim3(12, 128), 256, 0, stream>>>(Xc, Wtcat, bias, skip, z, qs);
    rscore_gemm_k<<<dim3(128, 4), 256, 0, stream>>>(Wkr, Xc, E, lsum);
    router_v_k<<<dim3(16, 32), 256, 0, stream>>>(E, lsum, Xc, tab, rV);
    final_attn_k<<<dim3(64, 8, 4), 256, 0, stream>>>(qs, rV, tab, skip, z, flag, d_out);
}

// Round 6
// 222.187 us; speedup vs baseline: 1.4754x; 1.0978x over previous
//
#include <hip/hip_runtime.h>

// RouterAttention on gfx950. B=4 L=S=4096 D=512 H=8 E=R=64.
// R6: (1) conflict-free XOR swizzle (term `row` not `row>>1`) in both GEMM
// bodies; (2) launch fusion: 13 -> 6 dispatches, gemm_fused || rscore_gemm in
// one 2048-block launch (3:1 interleave) for overlap + tail fill.

#define DEV __device__ __forceinline__

constexpr int Bn = 4, Ln = 4096, Dn = 512, Hn = 8, En = 64, Rn = 64;
constexpr int Sn = 4096;
constexpr float SCALE = 0.125f;                 // 1/sqrt(E)
constexpr float L2B_OVER_K = 13.287712379549449f / 32.0f; // log2(10000)/32

typedef __bf16 bf16x8 __attribute__((ext_vector_type(8)));
typedef float floatx4 __attribute__((ext_vector_type(4)));

DEV float bf2f(ushort u) { return __uint_as_float(((unsigned)u) << 16); }
DEV ushort f2bf(float f) {
    unsigned u = __float_as_uint(f);
    u += 0x7fffu + ((u >> 16) & 1u);            // RNE
    return (ushort)(u >> 16);
}
DEV bf16x8 ldsfrag(const ushort* p) { return *reinterpret_cast<const bf16x8*>(p); }
#define MFMA(a, b, c) __builtin_amdgcn_mfma_f32_16x16x32_bf16(a, b, c, 0, 0, 0)

DEV void gload16(const ushort* g, ushort* lds) {
    __builtin_amdgcn_global_load_lds(
        (const __attribute__((address_space(1))) unsigned int*)g,
        (__attribute__((address_space(3))) unsigned int*)lds, 16, 0, 0);
}

DEV int wave_sum_i(int v) {
    #pragma unroll
    for (int off = 1; off < 64; off <<= 1) v += __shfl_xor(v, off);
    return v;
}

// ---- dtype sniffer: flag=1 if x looks like f32, 0 if bf16-packed ----
__global__ __launch_bounds__(256) void sniff_k(const uint* __restrict__ x, int* __restrict__ flag) {
    int t = threadIdx.x, cnt = 0;
    #pragma unroll
    for (int i = 0; i < 16; ++i) {
        uint u = x[t * 16 + i];
        uint e = (u >> 7) & 0xFF;
        cnt += (e >= 100 && e <= 140) ? 1 : 0;
    }
    cnt = wave_sum_i(cnt);
    __shared__ int red[4];
    int w = t >> 6, l = t & 63;
    if (l == 0) red[w] = cnt;
    __syncthreads();
    if (t == 0) flag[0] = ((red[0] + red[1] + red[2] + red[3]) < 2048) ? 1 : 0;
}

constexpr size_t SEG1 = 8388608, SEG2 = 8650752, SEG3 = 8651264, SEG4 = 8913408,
                 SEG5 = 8913920, SEG6 = 9176064, SEG7 = 9176576, SEG8 = 9438720,
                 SEG9 = 9439232, SEGT = 9472000;

// ---- prep0: canon (9250 blk) + rope tab (512 blk) + zero rV/lsum (131 blk) ----
__global__ __launch_bounds__(256)
void prep0_k(const void* p0, const void* p1, const void* p2, const void* p3,
             const void* p4, const void* p5, const void* p6, const void* p7,
             const void* p8, const void* p9, const int* __restrict__ flag,
             ushort* __restrict__ dst, float2* __restrict__ tab,
             float* __restrict__ rV, float* __restrict__ lsum) {
    const int bid = blockIdx.x, tid = threadIdx.x;
    if (bid < 9250) {
        const int f = *flag;
        size_t i0 = (size_t)bid * 1024 + tid;
        #pragma unroll
        for (int r = 0; r < 4; ++r) {
            size_t i = i0 + (size_t)r * 256;
            if (i >= SEGT) return;
            const void* sp; size_t off;
            if      (i < SEG1) { sp = p0; off = i; }
            else if (i < SEG2) { sp = p1; off = i - SEG1; }
            else if (i < SEG3) { sp = p2; off = i - SEG2; }
            else if (i < SEG4) { sp = p3; off = i - SEG3; }
            else if (i < SEG5) { sp = p4; off = i - SEG4; }
            else if (i < SEG6) { sp = p5; off = i - SEG5; }
            else if (i < SEG7) { sp = p6; off = i - SEG6; }
            else if (i < SEG8) { sp = p7; off = i - SEG7; }
            else if (i < SEG9) { sp = p8; off = i - SEG8; }
            else               { sp = p9; off = i - SEG9; }
            dst[i] = f ? f2bf(((const float*)sp)[off]) : ((const ushort*)sp)[off];
        }
    } else if (bid < 9762) {
        int idx = (bid - 9250) * 256 + tid;     // 131072 entries
        int p = idx >> 5, j = idx & 31;
        float theta = exp2f(-(float)j * L2B_OVER_K);
        float ang = (float)(Sn - 1 - p) * theta;
        float s, c;
        sincosf(ang, &s, &c);
        tab[idx] = make_float2(c, s);
    } else {
        int base = (bid - 9762) * 1024 + tid;
        #pragma unroll
        for (int r = 0; r < 4; ++r) {
            int f32i = base + r * 256;
            if (f32i < 131072) rV[f32i] = 0.f;
            else if (f32i < 133120) lsum[f32i - 131072] = 0.f;
        }
    }
}

// ---- prep1: 2 transposes (128 blk) + prep_wr (128 blk) + prep_bias (1 blk) ----
__global__ __launch_bounds__(256)
void prep1_k(const ushort* __restrict__ Wskc, const ushort* __restrict__ Wzc,
             const ushort* __restrict__ Wqc, const ushort* __restrict__ Wkc,
             const ushort* __restrict__ RPc, const ushort* __restrict__ bqc,
             const ushort* __restrict__ bskc, const ushort* __restrict__ bzc,
             ushort* __restrict__ Wtcat, ushort* __restrict__ Wkr,
             float* __restrict__ biascat) {
    __shared__ ushort t64[64][65];
    __shared__ ushort As1[64][72];
    __shared__ ushort Bs1[64][72];
    const int bid = blockIdx.x, tid = threadIdx.x;
    if (bid < 128) {                            // transpose: Wt[dout][din]
        const ushort* W = (bid < 64) ? Wskc : Wzc;
        ushort* Wt = Wtcat + (bid < 64 ? 0 : 262144);
        int bb = bid & 63;
        int bx = (bb & 7) * 64, by = (bb >> 3) * 64;
        int c = tid & 63, r0 = (tid >> 6) * 16;
        #pragma unroll
        for (int i = 0; i < 16; ++i) t64[r0 + i][c] = W[(size_t)(by + r0 + i) * Dn + bx + c];
        __syncthreads();
        #pragma unroll
        for (int i = 0; i < 16; ++i) Wt[(size_t)(bx + r0 + i) * Dn + by + c] = t64[c][r0 + i];
    } else if (bid < 256) {                     // prep_wr
        int idx = bid - 128;
        int zsel = idx >> 6, rem = idx & 63;
        int d0 = (rem & 7) * 64, h = rem >> 3;
        const ushort* W = zsel ? Wkc : Wqc;
        ushort* Out = zsel ? Wkr : (Wtcat + 524288);
        #pragma unroll
        for (int j = 0; j < 2; ++j) {
            int lin = j * 256 + tid, row = lin >> 3, c = (lin & 7) * 8;
            *(uint4*)&As1[row][c] = *(const uint4*)&RPc[(size_t)row * Dn + h * En + c];
            *(uint4*)&Bs1[row][c] = *(const uint4*)&W[(size_t)(d0 + row) * Dn + h * En + c];
        }
        __syncthreads();
        const int w = tid >> 6, l = tid & 63;
        const int mt = (w >> 1) * 32, nt = (w & 1) * 32, lr = l & 15, lq = l >> 4;
        floatx4 acc[2][2] = {};
        #pragma unroll
        for (int ks = 0; ks < 64; ks += 32) {
            bf16x8 a0 = ldsfrag(&As1[mt + lr][ks + lq * 8]);
            bf16x8 a1 = ldsfrag(&As1[mt + 16 + lr][ks + lq * 8]);
            bf16x8 b0 = ldsfrag(&Bs1[nt + lr][ks + lq * 8]);
            bf16x8 b1 = ldsfrag(&Bs1[nt + 16 + lr][ks + lq * 8]);
            acc[0][0] = MFMA(a0, b0, acc[0][0]);
            acc[0][1] = MFMA(a0, b1, acc[0][1]);
            acc[1][0] = MFMA(a1, b0, acc[1][0]);
            acc[1][1] = MFMA(a1, b1, acc[1][1]);
        }
        #pragma unroll
        for (int mi = 0; mi < 2; ++mi)
            #pragma unroll
            for (int ni = 0; ni < 2; ++ni)
                #pragma unroll
                for (int ri = 0; ri < 4; ++ri) {
                    int ro = mt + mi * 16 + lq * 4 + ri;
                    int d = d0 + nt + ni * 16 + lr;
                    Out[(size_t)(h * En + ro) * Dn + d] = f2bf(acc[mi][ni][ri] * SCALE);
                }
    } else {                                    // prep_bias
        #pragma unroll
        for (int it = 0; it < 2; ++it) {
            int i = it * 256 + tid;
            biascat[i]       = bf2f(bskc[i]);
            biascat[512 + i] = bf2f(bzc[i]);
            int h = i >> 6, ro = i & 63;
            float s = 0.f;
            for (int e = 0; e < 64; ++e)
                s += bf2f(bqc[h * En + e]) * bf2f(RPc[(size_t)ro * Dn + h * En + e]);
            biascat[1024 + i] = s * SCALE;
        }
    }
}

// ---- shared 128x128x512 K-loop, conflict-free swizzle: slot s holds chunk
//      ((s&7) - row) & 7; read phases hit 8 distinct bank-quads. ----
DEV void kloop128(const ushort* __restrict__ Ag, const ushort* __restrict__ Bg,
                  int m0, int n0, ushort* As, ushort* Bs, int tid,
                  floatx4 (&acc)[4][4]) {
    const int w = tid >> 6, l = tid & 63;
    const int mt = (w >> 1) * 64, nt = (w & 1) * 64;
    const int lr = l & 15, lq = l >> 4;
    for (int kc = 0; kc < Dn; kc += 64) {
        __syncthreads();
        #pragma unroll
        for (int j = 0; j < 4; ++j) {
            int slot = (w * 4 + j) * 64 + l;            // lane-linear LDS slot
            int row = slot >> 3;
            int c = ((slot & 7) - row) & 7;             // swizzled global chunk
            gload16(&Ag[(size_t)(m0 + row) * Dn + kc + c * 8], &As[(w * 4 + j) * 512]);
            gload16(&Bg[(size_t)(n0 + row) * Dn + kc + c * 8], &Bs[(w * 4 + j) * 512]);
        }
        __syncthreads();
        #pragma unroll
        for (int ks = 0; ks < 64; ks += 32) {
            bf16x8 a[4], bb[4];
            const int cc = (ks >> 3) + lq;
            #pragma unroll
            for (int i = 0; i < 4; ++i) {
                int row = mt + 16 * i + lr;
                a[i] = ldsfrag(&As[(row * 8 + ((cc + row) & 7)) * 8]);
            }
            #pragma unroll
            for (int i = 0; i < 4; ++i) {
                int row = nt + 16 * i + lr;
                bb[i] = ldsfrag(&Bs[(row * 8 + ((cc + row) & 7)) * 8]);
            }
            #pragma unroll
            for (int mi = 0; mi < 4; ++mi)
                #pragma unroll
                for (int ni = 0; ni < 4; ++ni)
                    acc[mi][ni] = MFMA(a[mi], bb[ni], acc[mi][ni]);
        }
    }
}

// ---- big_k: gemm_fused (1536 blocks) || rscore_gemm (512 blocks), 3:1 ----
__global__ __launch_bounds__(256)
void big_k(const ushort* __restrict__ X, const ushort* __restrict__ Wtcat,
           const float* __restrict__ biascat, const ushort* __restrict__ Wkr,
           ushort* __restrict__ skip, ushort* __restrict__ z,
           ushort* __restrict__ qs, ushort* __restrict__ E,
           float* __restrict__ lsum) {
    __shared__ __align__(16) ushort As[8192];
    __shared__ __align__(16) ushort Bs[8192];
    const int bid = blockIdx.x, tid = threadIdx.x;
    const int w = tid >> 6, l = tid & 63;
    const int mt = (w >> 1) * 64, nt = (w & 1) * 64;
    const int lr = l & 15, lq = l >> 4;
    floatx4 acc[4][4] = {};
    if ((bid & 3) != 3) {                       // ---- projection GEMM ----
        int idx = (bid >> 2) * 3 + (bid & 3);   // 0..1535
        const int n0 = (idx % 12) * 128;
        const int m0 = (idx / 12) * 128;
        kloop128(X, Wtcat, m0, n0, As, Bs, tid, acc);
        const int sec = n0 >> 9;                // 0=skip 1=z 2=qs
        ushort* dst = sec == 0 ? skip : (sec == 1 ? z : qs);
        #pragma unroll
        for (int ni = 0; ni < 4; ++ni) {
            int ng = n0 + nt + ni * 16 + lr;
            float bbv = biascat[ng];
            int nc = ng & 511;
            #pragma unroll
            for (int mi = 0; mi < 4; ++mi)
                #pragma unroll
                for (int ri = 0; ri < 4; ++ri) {
                    int row = m0 + mt + mi * 16 + lq * 4 + ri;
                    float v = acc[mi][ni][ri] + bbv;
                    if (sec == 1) v = v / (1.0f + __expf(-v));
                    dst[(size_t)row * Dn + nc] = f2bf(v);
                }
        }
    } else {                                    // ---- router scores GEMM ----
        int idx = bid >> 2;                     // 0..511
        const int n0 = (idx & 127) * 128;       // x row = b*4096+s
        const int m0 = (idx >> 7) * 128;        // Wkr row = h*64+r
        kloop128(Wkr, X, m0, n0, As, Bs, tid, acc);
        const int b = n0 >> 12;
        const int sbase = (n0 & 4095) + nt;
        #pragma unroll
        for (int mi = 0; mi < 4; ++mi)
            #pragma unroll
            for (int ri = 0; ri < 4; ++ri) {
                size_t row = (size_t)(b * 512 + m0 + mt + mi * 16 + lq * 4 + ri);
                float rs = 0.f;
                #pragma unroll
                for (int ni = 0; ni < 4; ++ni) {
                    int s = sbase + ni * 16 + lr;
                    float e = __expf(acc[mi][ni][ri]);
                    E[row * Sn + s] = f2bf(e);
                    rs += e;
                }
                rs += __shfl_xor(rs, 1); rs += __shfl_xor(rs, 2);
                rs += __shfl_xor(rs, 4); rs += __shfl_xor(rs, 8);
                if (lr == 0) atomicAdd(&lsum[row], rs);
            }
    }
}

// ---- rV[bh][r][e] += sum_s rope(E/l)[r][s] * v[s][e] ----
__global__ __launch_bounds__(256)
void router_v_k(const ushort* __restrict__ E, const float* __restrict__ lsum,
                const ushort* __restrict__ X, const float2* __restrict__ tab,
                float* __restrict__ rV) {
    __shared__ ushort As[64][72];
    __shared__ ushort Bs[64][72];
    __shared__ float invl[64];
    const int tid = threadIdx.x;
    const int bh = blockIdx.y, b = bh >> 3, h = bh & 7;
    const int w = tid >> 6, l = tid & 63;
    const int mt = (w >> 1) * 32, nt = (w & 1) * 32, lr = l & 15, lq = l >> 4;
    if (tid < 64) invl[tid] = 1.0f / lsum[(size_t)bh * Rn + tid];
    floatx4 acc[2][2] = {};
    for (int t4 = 0; t4 < 4; ++t4) {
        const int sb = blockIdx.x * 256 + t4 * 64;
        __syncthreads();
        #pragma unroll
        for (int i = 0; i < 8; ++i) {
            int lin = i * 256 + tid;
            int j = lin >> 6, sl = lin & 63;
            int sg2 = sb + sl;
            float pe = bf2f(E[((size_t)bh * Rn + 2 * j) * Sn + sg2]) * invl[2 * j];
            float po = bf2f(E[((size_t)bh * Rn + 2 * j + 1) * Sn + sg2]) * invl[2 * j + 1];
            float2 cs = tab[sg2 * 32 + j];
            As[2 * j][sl]     = f2bf(pe * cs.x - po * cs.y);
            As[2 * j + 1][sl] = f2bf(pe * cs.y + po * cs.x);
        }
        #pragma unroll
        for (int i = 0; i < 16; ++i) {
            int lin = i * 256 + tid;
            int sl = lin >> 6, e = lin & 63;
            Bs[e][sl] = X[(size_t)(b * Ln + sb + sl) * Dn + h * En + e];
        }
        __syncthreads();
        #pragma unroll
        for (int ks = 0; ks < 64; ks += 32) {
            bf16x8 a0 = ldsfrag(&As[mt + lr][ks + lq * 8]);
            bf16x8 a1 = ldsfrag(&As[mt + 16 + lr][ks + lq * 8]);
            bf16x8 b0 = ldsfrag(&Bs[nt + lr][ks + lq * 8]);
            bf16x8 b1 = ldsfrag(&Bs[nt + 16 + lr][ks + lq * 8]);
            acc[0][0] = MFMA(a0, b0, acc[0][0]);
            acc[0][1] = MFMA(a0, b1, acc[0][1]);
            acc[1][0] = MFMA(a1, b0, acc[1][0]);
            acc[1][1] = MFMA(a1, b1, acc[1][1]);
        }
    }
    #pragma unroll
    for (int mi = 0; mi < 2; ++mi)
        #pragma unroll
        for (int ni = 0; ni < 2; ++ni)
            #pragma unroll
            for (int ri = 0; ri < 4; ++ri) {
                int r = mt + mi * 16 + lq * 4 + ri;
                int e = nt + ni * 16 + lr;
                atomicAdd(&rV[((size_t)bh * Rn + r) * En + e], acc[mi][ni][ri]);
            }
}

// ---- fused query path: qs -> in-thread softmax -> rope -> @rV -> (+skip)*z ----
__global__ __launch_bounds__(256)
void final_attn_k(const ushort* __restrict__ QS, const float* __restrict__ rV,
                  const float2* __restrict__ tab, const ushort* __restrict__ Skip,
                  const ushort* __restrict__ Zs, const int* __restrict__ flagp,
                  void* __restrict__ Outv) {
    __shared__ ushort Ap[64][72];
    __shared__ ushort BvT[64][72];
    const int f = *flagp;
    const int tid = threadIdx.x;
    const int h = blockIdx.y, b = blockIdx.z, bh = b * Hn + h;
    const int l0 = blockIdx.x * 64;
    const int w = tid >> 6, l = tid & 63;
    const int mt = (w >> 1) * 32, nt = (w & 1) * 32, lr = l & 15, lq = l >> 4;
    #pragma unroll
    for (int i = 0; i < 16; ++i) {
        int lin = i * 256 + tid, r = lin >> 6, e = lin & 63;
        BvT[e][r] = f2bf(rV[((size_t)bh * Rn + r) * En + e]);
    }
    {   // quad-per-token softmax + rope
        const int lt = tid >> 2, qd = tid & 3;
        const ushort* qrow = &QS[(size_t)(b * Ln + l0 + lt) * Dn + h * En + qd * 16];
        uint4 u0 = ((const uint4*)qrow)[0];
        uint4 u1 = ((const uint4*)qrow)[1];
        uint uw[8] = {u0.x, u0.y, u0.z, u0.w, u1.x, u1.y, u1.z, u1.w};
        float p[16];
        float s = 0.f;
        #pragma unroll
        for (int j = 0; j < 8; ++j) {
            float flo = __uint_as_float(uw[j] << 16);
            float fhi = __uint_as_float(uw[j] & 0xffff0000u);
            float e0 = __expf(flo), e1 = __expf(fhi);
            p[2 * j] = e0; p[2 * j + 1] = e1;
            s += e0 + e1;
        }
        s += __shfl_xor(s, 1);
        s += __shfl_xor(s, 2);
        float inv = 1.0f / s;
        #pragma unroll
        for (int u = 0; u < 8; ++u) {
            float A0 = p[2 * u] * inv, A1 = p[2 * u + 1] * inv;
            float2 cs = tab[(l0 + lt) * 32 + qd * 8 + u];
            Ap[lt][qd * 16 + 2 * u]     = f2bf(A0 * cs.x - A1 * cs.y);
            Ap[lt][qd * 16 + 2 * u + 1] = f2bf(A0 * cs.y + A1 * cs.x);
        }
    }
    __syncthreads();
    floatx4 acc[2][2] = {};
    #pragma unroll
    for (int ks = 0; ks < 64; ks += 32) {
        bf16x8 a0 = ldsfrag(&Ap[mt + lr][ks + lq * 8]);
        bf16x8 a1 = ldsfrag(&Ap[mt + 16 + lr][ks + lq * 8]);
        bf16x8 b0 = ldsfrag(&BvT[nt + lr][ks + lq * 8]);
        bf16x8 b1 = ldsfrag(&BvT[nt + 16 + lr][ks + lq * 8]);
        acc[0][0] = MFMA(a0, b0, acc[0][0]);
        acc[0][1] = MFMA(a0, b1, acc[0][1]);
        acc[1][0] = MFMA(a1, b0, acc[1][0]);
        acc[1][1] = MFMA(a1, b1, acc[1][1]);
    }
    #pragma unroll
    for (int mi = 0; mi < 2; ++mi)
        #pragma unroll
        for (int ni = 0; ni < 2; ++ni)
            #pragma unroll
            for (int ri = 0; ri < 4; ++ri) {
                int row = mt + mi * 16 + lq * 4 + ri;
                int e = nt + ni * 16 + lr;
                size_t idx = (size_t)(b * Ln + l0 + row) * Dn + h * En + e;
                float v = acc[mi][ni][ri];
                float val = (v + bf2f(Skip[idx])) * bf2f(Zs[idx]);
                if (f) ((float*)Outv)[idx] = val;
                else   ((ushort*)Outv)[idx] = f2bf(val);
            }
}

extern "C" void kernel_launch(void* const* d_in, const int* in_sizes, int n_in,
                              void* d_out, int out_size, void* d_ws, size_t ws_size,
                              hipStream_t stream) {
    const size_t OFF_SK    = 0;                  // 16 MiB bf16 [16384][512]
    const size_t OFF_Z     = 16777216;
    const size_t OFF_QS    = 33554432;
    const size_t OFF_E     = 50331648;           // 16 MiB bf16 E
    const size_t OFF_RV    = 67108864;           // 512 KiB f32
    const size_t OFF_L     = 67633152;           // 8 KiB f32 lsum
    const size_t OFF_TAB   = 67641344;           // 1 MiB
    const size_t OFF_WT    = 68689920;           // Wtcat 1536x512 bf16 = 1.5 MiB
    const size_t OFF_WKR   = 70262784;           // 512x512 bf16
    const size_t OFF_BIAS  = 70787072;           // 1536 f32
    const size_t OFF_CANON = 70793216;           // 18,944,000 B
    const size_t OFF_FLAG  = OFF_CANON + 18944000;
    const size_t NEED      = OFF_FLAG + 16;      // ~89.8 MB
    if (ws_size < NEED) return;

    char* ws = (char*)d_ws;
    ushort* skip  = (ushort*)(ws + OFF_SK);
    ushort* z     = (ushort*)(ws + OFF_Z);
    ushort* qs    = (ushort*)(ws + OFF_QS);
    ushort* E     = (ushort*)(ws + OFF_E);
    float*  rV    = (float*)(ws + OFF_RV);
    float*  lsum  = (float*)(ws + OFF_L);
    float2* tab   = (float2*)(ws + OFF_TAB);
    ushort* Wtcat = (ushort*)(ws + OFF_WT);
    ushort* Wkr   = (ushort*)(ws + OFF_WKR);
    float*  bias  = (float*)(ws + OFF_BIAS);
    ushort* canon = (ushort*)(ws + OFF_CANON);
    int*    flag  = (int*)(ws + OFF_FLAG);

    const ushort* Xc   = canon;
    const ushort* Wqc  = canon + SEG1;
    const ushort* bqc  = canon + SEG2;
    const ushort* Wkc  = canon + SEG3;
    const ushort* Wskc = canon + SEG5;
    const ushort* bskc = canon + SEG6;
    const ushort* Wzc  = canon + SEG7;
    const ushort* bzc  = canon + SEG8;
    const ushort* RPc  = canon + SEG9;

    sniff_k<<<1, 256, 0, stream>>>((const uint*)d_in[0], flag);
    prep0_k<<<9893, 256, 0, stream>>>(d_in[0], d_in[1], d_in[2], d_in[3], d_in[4],
                                      d_in[5], d_in[6], d_in[7], d_in[8], d_in[9],
                                      flag, canon, tab, rV, lsum);
    prep1_k<<<257, 256, 0, stream>>>(Wskc, Wzc, Wqc, Wkc, RPc, bqc, bskc, bzc,
                                     Wtcat, Wkr, bias);
    big_k<<<2048, 256, 0, stream>>>(Xc, Wtcat, bias, Wkr, skip, z, qs, E, lsum);
    router_v_k<<<dim3(16, 32), 256, 0, stream>>>(E, lsum, Xc, tab, rV);
    final_attn_k<<<dim3(64, 8, 4), 256, 0, stream>>>(qs, rV, tab, skip, z, flag, d_out);
}

// Round 7
// 211.973 us; speedup vs baseline: 1.5465x; 1.0482x over previous
//
#include <hip/hip_runtime.h>

// RouterAttention on gfx950. B=4 L=S=4096 D=512 H=8 E=R=64.
// R7: tail attack — (1) router_v: single-stage K=128 blocks (2 barriers, 1024
// blocks, coalesced tab_jp); (2) final_attn: LDS-transposed vectorized
// epilogue; (3) prep0 canon vectorized 8 elems/thread.

#define DEV __device__ __forceinline__

constexpr int Bn = 4, Ln = 4096, Dn = 512, Hn = 8, En = 64, Rn = 64;
constexpr int Sn = 4096;
constexpr float SCALE = 0.125f;                 // 1/sqrt(E)
constexpr float L2B_OVER_K = 13.287712379549449f / 32.0f; // log2(10000)/32

typedef __bf16 bf16x8 __attribute__((ext_vector_type(8)));
typedef float floatx4 __attribute__((ext_vector_type(4)));

DEV float bf2f(ushort u) { return __uint_as_float(((unsigned)u) << 16); }
DEV ushort f2bf(float f) {
    unsigned u = __float_as_uint(f);
    u += 0x7fffu + ((u >> 16) & 1u);            // RNE
    return (ushort)(u >> 16);
}
DEV bf16x8 ldsfrag(const ushort* p) { return *reinterpret_cast<const bf16x8*>(p); }
#define MFMA(a, b, c) __builtin_amdgcn_mfma_f32_16x16x32_bf16(a, b, c, 0, 0, 0)

DEV void gload16(const ushort* g, ushort* lds) {
    __builtin_amdgcn_global_load_lds(
        (const __attribute__((address_space(1))) unsigned int*)g,
        (__attribute__((address_space(3))) unsigned int*)lds, 16, 0, 0);
}

DEV int wave_sum_i(int v) {
    #pragma unroll
    for (int off = 1; off < 64; off <<= 1) v += __shfl_xor(v, off);
    return v;
}

// ---- dtype sniffer: flag=1 if x looks like f32, 0 if bf16-packed ----
__global__ __launch_bounds__(256) void sniff_k(const uint* __restrict__ x, int* __restrict__ flag) {
    int t = threadIdx.x, cnt = 0;
    #pragma unroll
    for (int i = 0; i < 16; ++i) {
        uint u = x[t * 16 + i];
        uint e = (u >> 7) & 0xFF;
        cnt += (e >= 100 && e <= 140) ? 1 : 0;
    }
    cnt = wave_sum_i(cnt);
    __shared__ int red[4];
    int w = t >> 6, l = t & 63;
    if (l == 0) red[w] = cnt;
    __syncthreads();
    if (t == 0) flag[0] = ((red[0] + red[1] + red[2] + red[3]) < 2048) ? 1 : 0;
}

constexpr size_t SEG1 = 8388608, SEG2 = 8650752, SEG3 = 8651264, SEG4 = 8913408,
                 SEG5 = 8913920, SEG6 = 9176064, SEG7 = 9176576, SEG8 = 9438720,
                 SEG9 = 9439232, SEGT = 9472000;

// ---- prep0: canon vec8 (4625 blk) + rope tabs (512 blk) + zero (131 blk) ----
__global__ __launch_bounds__(256)
void prep0_k(const void* p0, const void* p1, const void* p2, const void* p3,
             const void* p4, const void* p5, const void* p6, const void* p7,
             const void* p8, const void* p9, const int* __restrict__ flag,
             ushort* __restrict__ dst, float2* __restrict__ tab_pj,
             float2* __restrict__ tab_jp, float* __restrict__ rV,
             float* __restrict__ lsum) {
    const int bid = blockIdx.x, tid = threadIdx.x;
    if (bid < 4625) {                           // canon: 8 elems/thread
        const int f = *flag;
        size_t i = ((size_t)bid * 256 + tid) * 8;   // all SEG bounds %8==0
        const void* sp; size_t off;
        if      (i < SEG1) { sp = p0; off = i; }
        else if (i < SEG2) { sp = p1; off = i - SEG1; }
        else if (i < SEG3) { sp = p2; off = i - SEG2; }
        else if (i < SEG4) { sp = p3; off = i - SEG3; }
        else if (i < SEG5) { sp = p4; off = i - SEG4; }
        else if (i < SEG6) { sp = p5; off = i - SEG5; }
        else if (i < SEG7) { sp = p6; off = i - SEG6; }
        else if (i < SEG8) { sp = p7; off = i - SEG7; }
        else if (i < SEG9) { sp = p8; off = i - SEG8; }
        else               { sp = p9; off = i - SEG9; }
        ushort o8[8];
        if (f) {
            float4 a = *((const float4*)((const float*)sp + off));
            float4 b = *((const float4*)((const float*)sp + off) + 1);
            o8[0] = f2bf(a.x); o8[1] = f2bf(a.y); o8[2] = f2bf(a.z); o8[3] = f2bf(a.w);
            o8[4] = f2bf(b.x); o8[5] = f2bf(b.y); o8[6] = f2bf(b.z); o8[7] = f2bf(b.w);
        } else {
            *(uint4*)o8 = *(const uint4*)((const ushort*)sp + off);
        }
        *(uint4*)&dst[i] = *(uint4*)o8;
    } else if (bid < 5137) {                    // rope tables (both layouts)
        int idx = (bid - 4625) * 256 + tid;     // 131072 entries
        int p = idx >> 5, j = idx & 31;
        float theta = exp2f(-(float)j * L2B_OVER_K);
        float ang = (float)(Sn - 1 - p) * theta;
        float s, c;
        sincosf(ang, &s, &c);
        tab_pj[idx] = make_float2(c, s);
        tab_jp[j * Sn + p] = make_float2(c, s);
    } else {                                    // zero rV + lsum
        int base = (bid - 5137) * 1024 + tid;
        #pragma unroll
        for (int r = 0; r < 4; ++r) {
            int f32i = base + r * 256;
            if (f32i < 131072) rV[f32i] = 0.f;
            else if (f32i < 133120) lsum[f32i - 131072] = 0.f;
        }
    }
}

// ---- prep1: 2 transposes (128 blk) + prep_wr (128 blk) + prep_bias (1 blk) ----
__global__ __launch_bounds__(256)
void prep1_k(const ushort* __restrict__ Wskc, const ushort* __restrict__ Wzc,
             const ushort* __restrict__ Wqc, const ushort* __restrict__ Wkc,
             const ushort* __restrict__ RPc, const ushort* __restrict__ bqc,
             const ushort* __restrict__ bskc, const ushort* __restrict__ bzc,
             ushort* __restrict__ Wtcat, ushort* __restrict__ Wkr,
             float* __restrict__ biascat) {
    __shared__ ushort t64[64][65];
    __shared__ ushort As1[64][72];
    __shared__ ushort Bs1[64][72];
    const int bid = blockIdx.x, tid = threadIdx.x;
    if (bid < 128) {                            // transpose: Wt[dout][din]
        const ushort* W = (bid < 64) ? Wskc : Wzc;
        ushort* Wt = Wtcat + (bid < 64 ? 0 : 262144);
        int bb = bid & 63;
        int bx = (bb & 7) * 64, by = (bb >> 3) * 64;
        int c = tid & 63, r0 = (tid >> 6) * 16;
        #pragma unroll
        for (int i = 0; i < 16; ++i) t64[r0 + i][c] = W[(size_t)(by + r0 + i) * Dn + bx + c];
        __syncthreads();
        #pragma unroll
        for (int i = 0; i < 16; ++i) Wt[(size_t)(bx + r0 + i) * Dn + by + c] = t64[c][r0 + i];
    } else if (bid < 256) {                     // prep_wr
        int idx = bid - 128;
        int zsel = idx >> 6, rem = idx & 63;
        int d0 = (rem & 7) * 64, h = rem >> 3;
        const ushort* W = zsel ? Wkc : Wqc;
        ushort* Out = zsel ? Wkr : (Wtcat + 524288);
        #pragma unroll
        for (int j = 0; j < 2; ++j) {
            int lin = j * 256 + tid, row = lin >> 3, c = (lin & 7) * 8;
            *(uint4*)&As1[row][c] = *(const uint4*)&RPc[(size_t)row * Dn + h * En + c];
            *(uint4*)&Bs1[row][c] = *(const uint4*)&W[(size_t)(d0 + row) * Dn + h * En + c];
        }
        __syncthreads();
        const int w = tid >> 6, l = tid & 63;
        const int mt = (w >> 1) * 32, nt = (w & 1) * 32, lr = l & 15, lq = l >> 4;
        floatx4 acc[2][2] = {};
        #pragma unroll
        for (int ks = 0; ks < 64; ks += 32) {
            bf16x8 a0 = ldsfrag(&As1[mt + lr][ks + lq * 8]);
            bf16x8 a1 = ldsfrag(&As1[mt + 16 + lr][ks + lq * 8]);
            bf16x8 b0 = ldsfrag(&Bs1[nt + lr][ks + lq * 8]);
            bf16x8 b1 = ldsfrag(&Bs1[nt + 16 + lr][ks + lq * 8]);
            acc[0][0] = MFMA(a0, b0, acc[0][0]);
            acc[0][1] = MFMA(a0, b1, acc[0][1]);
            acc[1][0] = MFMA(a1, b0, acc[1][0]);
            acc[1][1] = MFMA(a1, b1, acc[1][1]);
        }
        #pragma unroll
        for (int mi = 0; mi < 2; ++mi)
            #pragma unroll
            for (int ni = 0; ni < 2; ++ni)
                #pragma unroll
                for (int ri = 0; ri < 4; ++ri) {
                    int ro = mt + mi * 16 + lq * 4 + ri;
                    int d = d0 + nt + ni * 16 + lr;
                    Out[(size_t)(h * En + ro) * Dn + d] = f2bf(acc[mi][ni][ri] * SCALE);
                }
    } else {                                    // prep_bias
        #pragma unroll
        for (int it = 0; it < 2; ++it) {
            int i = it * 256 + tid;
            biascat[i]       = bf2f(bskc[i]);
            biascat[512 + i] = bf2f(bzc[i]);
            int h = i >> 6, ro = i & 63;
            float s = 0.f;
            for (int e = 0; e < 64; ++e)
                s += bf2f(bqc[h * En + e]) * bf2f(RPc[(size_t)ro * Dn + h * En + e]);
            biascat[1024 + i] = s * SCALE;
        }
    }
}

// ---- shared 128x128x512 K-loop, conflict-free swizzle ----
DEV void kloop128(const ushort* __restrict__ Ag, const ushort* __restrict__ Bg,
                  int m0, int n0, ushort* As, ushort* Bs, int tid,
                  floatx4 (&acc)[4][4]) {
    const int w = tid >> 6, l = tid & 63;
    const int mt = (w >> 1) * 64, nt = (w & 1) * 64;
    const int lr = l & 15, lq = l >> 4;
    for (int kc = 0; kc < Dn; kc += 64) {
        __syncthreads();
        #pragma unroll
        for (int j = 0; j < 4; ++j) {
            int slot = (w * 4 + j) * 64 + l;
            int row = slot >> 3;
            int c = ((slot & 7) - row) & 7;
            gload16(&Ag[(size_t)(m0 + row) * Dn + kc + c * 8], &As[(w * 4 + j) * 512]);
            gload16(&Bg[(size_t)(n0 + row) * Dn + kc + c * 8], &Bs[(w * 4 + j) * 512]);
        }
        __syncthreads();
        #pragma unroll
        for (int ks = 0; ks < 64; ks += 32) {
            bf16x8 a[4], bb[4];
            const int cc = (ks >> 3) + lq;
            #pragma unroll
            for (int i = 0; i < 4; ++i) {
                int row = mt + 16 * i + lr;
                a[i] = ldsfrag(&As[(row * 8 + ((cc + row) & 7)) * 8]);
            }
            #pragma unroll
            for (int i = 0; i < 4; ++i) {
                int row = nt + 16 * i + lr;
                bb[i] = ldsfrag(&Bs[(row * 8 + ((cc + row) & 7)) * 8]);
            }
            #pragma unroll
            for (int mi = 0; mi < 4; ++mi)
                #pragma unroll
                for (int ni = 0; ni < 4; ++ni)
                    acc[mi][ni] = MFMA(a[mi], bb[ni], acc[mi][ni]);
        }
    }
}

// ---- big_k: gemm_fused (1536 blocks) || rscore_gemm (512 blocks), 3:1 ----
__global__ __launch_bounds__(256)
void big_k(const ushort* __restrict__ X, const ushort* __restrict__ Wtcat,
           const float* __restrict__ biascat, const ushort* __restrict__ Wkr,
           ushort* __restrict__ skip, ushort* __restrict__ z,
           ushort* __restrict__ qs, ushort* __restrict__ E,
           float* __restrict__ lsum) {
    __shared__ __align__(16) ushort As[8192];
    __shared__ __align__(16) ushort Bs[8192];
    const int bid = blockIdx.x, tid = threadIdx.x;
    const int w = tid >> 6, l = tid & 63;
    const int mt = (w >> 1) * 64, nt = (w & 1) * 64;
    const int lr = l & 15, lq = l >> 4;
    floatx4 acc[4][4] = {};
    if ((bid & 3) != 3) {                       // ---- projection GEMM ----
        int idx = (bid >> 2) * 3 + (bid & 3);   // 0..1535
        const int n0 = (idx % 12) * 128;
        const int m0 = (idx / 12) * 128;
        kloop128(X, Wtcat, m0, n0, As, Bs, tid, acc);
        const int sec = n0 >> 9;                // 0=skip 1=z 2=qs
        ushort* dst = sec == 0 ? skip : (sec == 1 ? z : qs);
        #pragma unroll
        for (int ni = 0; ni < 4; ++ni) {
            int ng = n0 + nt + ni * 16 + lr;
            float bbv = biascat[ng];
            int nc = ng & 511;
            #pragma unroll
            for (int mi = 0; mi < 4; ++mi)
                #pragma unroll
                for (int ri = 0; ri < 4; ++ri) {
                    int row = m0 + mt + mi * 16 + lq * 4 + ri;
                    float v = acc[mi][ni][ri] + bbv;
                    if (sec == 1) v = v / (1.0f + __expf(-v));
                    dst[(size_t)row * Dn + nc] = f2bf(v);
                }
        }
    } else {                                    // ---- router scores GEMM ----
        int idx = bid >> 2;                     // 0..511
        const int n0 = (idx & 127) * 128;       // x row = b*4096+s
        const int m0 = (idx >> 7) * 128;        // Wkr row = h*64+r
        kloop128(Wkr, X, m0, n0, As, Bs, tid, acc);
        const int b = n0 >> 12;
        const int sbase = (n0 & 4095) + nt;
        #pragma unroll
        for (int mi = 0; mi < 4; ++mi)
            #pragma unroll
            for (int ri = 0; ri < 4; ++ri) {
                size_t row = (size_t)(b * 512 + m0 + mt + mi * 16 + lq * 4 + ri);
                float rs = 0.f;
                #pragma unroll
                for (int ni = 0; ni < 4; ++ni) {
                    int s = sbase + ni * 16 + lr;
                    float e = __expf(acc[mi][ni][ri]);
                    E[row * Sn + s] = f2bf(e);
                    rs += e;
                }
                rs += __shfl_xor(rs, 1); rs += __shfl_xor(rs, 2);
                rs += __shfl_xor(rs, 4); rs += __shfl_xor(rs, 8);
                if (lr == 0) atomicAdd(&lsum[row], rs);
            }
    }
}

// ---- rV[bh][r][e] += sum_s rope(E/l)[r][s] * v[s][e]; K=128 single-stage ----
__global__ __launch_bounds__(256)
void router_v_k(const ushort* __restrict__ E, const float* __restrict__ lsum,
                const ushort* __restrict__ X, const float2* __restrict__ tab_jp,
                float* __restrict__ rV) {
    __shared__ ushort As[64][136];   // rope(E/l)[r][s0..127]
    __shared__ ushort Bs[64][136];   // v^T[e][s]
    __shared__ float invl[64];
    const int tid = threadIdx.x;
    const int bh = blockIdx.y, b = bh >> 3, h = bh & 7;
    const int sb = blockIdx.x * 128;
    if (tid < 64) invl[tid] = 1.0f / lsum[(size_t)bh * Rn + tid];
    __syncthreads();
    #pragma unroll
    for (int it = 0; it < 16; ++it) {           // rope staging: (j, s)
        int lin = it * 256 + tid;
        int j = lin >> 7, sl = lin & 127;
        int sg = sb + sl;
        float pe = bf2f(E[((size_t)bh * Rn + 2 * j) * Sn + sg]) * invl[2 * j];
        float po = bf2f(E[((size_t)bh * Rn + 2 * j + 1) * Sn + sg]) * invl[2 * j + 1];
        float2 cs = tab_jp[j * Sn + sg];        // coalesced in s
        As[2 * j][sl]     = f2bf(pe * cs.x - po * cs.y);
        As[2 * j + 1][sl] = f2bf(pe * cs.y + po * cs.x);
    }
    #pragma unroll
    for (int it = 0; it < 4; ++it) {            // v^T staging, uint4 loads
        int lin = it * 256 + tid;
        int s = lin >> 3, eg = (lin & 7) * 8;
        ushort u8[8];
        *(uint4*)u8 = *(const uint4*)&X[(size_t)(b * Ln + sb + s) * Dn + h * En + eg];
        #pragma unroll
        for (int t = 0; t < 8; ++t) Bs[eg + t][s] = u8[t];
    }
    __syncthreads();
    const int w = tid >> 6, l = tid & 63;
    const int mt = (w >> 1) * 32, nt = (w & 1) * 32, lr = l & 15, lq = l >> 4;
    floatx4 acc[2][2] = {};
    #pragma unroll
    for (int ks = 0; ks < 128; ks += 32) {
        bf16x8 a0 = ldsfrag(&As[mt + lr][ks + lq * 8]);
        bf16x8 a1 = ldsfrag(&As[mt + 16 + lr][ks + lq * 8]);
        bf16x8 b0 = ldsfrag(&Bs[nt + lr][ks + lq * 8]);
        bf16x8 b1 = ldsfrag(&Bs[nt + 16 + lr][ks + lq * 8]);
        acc[0][0] = MFMA(a0, b0, acc[0][0]);
        acc[0][1] = MFMA(a0, b1, acc[0][1]);
        acc[1][0] = MFMA(a1, b0, acc[1][0]);
        acc[1][1] = MFMA(a1, b1, acc[1][1]);
    }
    #pragma unroll
    for (int mi = 0; mi < 2; ++mi)
        #pragma unroll
        for (int ni = 0; ni < 2; ++ni)
            #pragma unroll
            for (int ri = 0; ri < 4; ++ri) {
                int r = mt + mi * 16 + lq * 4 + ri;
                int e = nt + ni * 16 + lr;
                atomicAdd(&rV[((size_t)bh * Rn + r) * En + e], acc[mi][ni][ri]);
            }
}

// ---- fused query path: qs -> in-thread softmax -> rope -> @rV -> (+skip)*z ----
__global__ __launch_bounds__(256)
void final_attn_k(const ushort* __restrict__ QS, const float* __restrict__ rV,
                  const float2* __restrict__ tab_pj, const ushort* __restrict__ Skip,
                  const ushort* __restrict__ Zs, const int* __restrict__ flagp,
                  void* __restrict__ Outv) {
    __shared__ ushort Ap[64][72];
    __shared__ ushort BvT[64][72];
    __shared__ float Cs[64][68];
    const int f = *flagp;
    const int tid = threadIdx.x;
    const int h = blockIdx.y, b = blockIdx.z, bh = b * Hn + h;
    const int l0 = blockIdx.x * 64;
    const int w = tid >> 6, l = tid & 63;
    const int mt = (w >> 1) * 32, nt = (w & 1) * 32, lr = l & 15, lq = l >> 4;
    #pragma unroll
    for (int i = 0; i < 16; ++i) {
        int lin = i * 256 + tid, r = lin >> 6, e = lin & 63;
        BvT[e][r] = f2bf(rV[((size_t)bh * Rn + r) * En + e]);
    }
    {   // quad-per-token softmax + rope
        const int lt = tid >> 2, qd = tid & 3;
        const ushort* qrow = &QS[(size_t)(b * Ln + l0 + lt) * Dn + h * En + qd * 16];
        uint4 u0 = ((const uint4*)qrow)[0];
        uint4 u1 = ((const uint4*)qrow)[1];
        uint uw[8] = {u0.x, u0.y, u0.z, u0.w, u1.x, u1.y, u1.z, u1.w};
        float p[16];
        float s = 0.f;
        #pragma unroll
        for (int j = 0; j < 8; ++j) {
            float flo = __uint_as_float(uw[j] << 16);
            float fhi = __uint_as_float(uw[j] & 0xffff0000u);
            float e0 = __expf(flo), e1 = __expf(fhi);
            p[2 * j] = e0; p[2 * j + 1] = e1;
            s += e0 + e1;
        }
        s += __shfl_xor(s, 1);
        s += __shfl_xor(s, 2);
        float inv = 1.0f / s;
        #pragma unroll
        for (int u = 0; u < 8; ++u) {
            float A0 = p[2 * u] * inv, A1 = p[2 * u + 1] * inv;
            float2 cs = tab_pj[(l0 + lt) * 32 + qd * 8 + u];
            Ap[lt][qd * 16 + 2 * u]     = f2bf(A0 * cs.x - A1 * cs.y);
            Ap[lt][qd * 16 + 2 * u + 1] = f2bf(A0 * cs.y + A1 * cs.x);
        }
    }
    __syncthreads();
    floatx4 acc[2][2] = {};
    #pragma unroll
    for (int ks = 0; ks < 64; ks += 32) {
        bf16x8 a0 = ldsfrag(&Ap[mt + lr][ks + lq * 8]);
        bf16x8 a1 = ldsfrag(&Ap[mt + 16 + lr][ks + lq * 8]);
        bf16x8 b0 = ldsfrag(&BvT[nt + lr][ks + lq * 8]);
        bf16x8 b1 = ldsfrag(&BvT[nt + 16 + lr][ks + lq * 8]);
        acc[0][0] = MFMA(a0, b0, acc[0][0]);
        acc[0][1] = MFMA(a0, b1, acc[0][1]);
        acc[1][0] = MFMA(a1, b0, acc[1][0]);
        acc[1][1] = MFMA(a1, b1, acc[1][1]);
    }
    #pragma unroll
    for (int mi = 0; mi < 2; ++mi)
        #pragma unroll
        for (int ni = 0; ni < 2; ++ni)
            #pragma unroll
            for (int ri = 0; ri < 4; ++ri)
                Cs[mt + mi * 16 + lq * 4 + ri][nt + ni * 16 + lr] = acc[mi][ni][ri];
    __syncthreads();
    {   // vectorized epilogue: thread = (token, 16-e group)
        const int token = tid >> 2, e0 = (tid & 3) * 16;
        size_t base = (size_t)(b * Ln + l0 + token) * Dn + h * En + e0;
        uint4 sk0 = *(const uint4*)&Skip[base];
        uint4 sk1 = *(const uint4*)&Skip[base + 8];
        uint4 zz0 = *(const uint4*)&Zs[base];
        uint4 zz1 = *(const uint4*)&Zs[base + 8];
        uint sks[8] = {sk0.x, sk0.y, sk0.z, sk0.w, sk1.x, sk1.y, sk1.z, sk1.w};
        uint zzs[8] = {zz0.x, zz0.y, zz0.z, zz0.w, zz1.x, zz1.y, zz1.z, zz1.w};
        float ov[16];
        #pragma unroll
        for (int j = 0; j < 8; ++j) {
            float s0 = __uint_as_float(sks[j] << 16);
            float s1 = __uint_as_float(sks[j] & 0xffff0000u);
            float z0 = __uint_as_float(zzs[j] << 16);
            float z1 = __uint_as_float(zzs[j] & 0xffff0000u);
            ov[2 * j]     = (Cs[token][e0 + 2 * j] + s0) * z0;
            ov[2 * j + 1] = (Cs[token][e0 + 2 * j + 1] + s1) * z1;
        }
        if (f) {
            float* op = (float*)Outv + base;
            #pragma unroll
            for (int q = 0; q < 4; ++q)
                *(float4*)(op + 4 * q) = make_float4(ov[4 * q], ov[4 * q + 1],
                                                     ov[4 * q + 2], ov[4 * q + 3]);
        } else {
            ushort o16[16];
            #pragma unroll
            for (int t = 0; t < 16; ++t) o16[t] = f2bf(ov[t]);
            *(uint4*)((ushort*)Outv + base)     = *(uint4*)o16;
            *(uint4*)((ushort*)Outv + base + 8) = *(uint4*)(o16 + 8);
        }
    }
}

extern "C" void kernel_launch(void* const* d_in, const int* in_sizes, int n_in,
                              void* d_out, int out_size, void* d_ws, size_t ws_size,
                              hipStream_t stream) {
    const size_t OFF_SK    = 0;                  // 16 MiB bf16 [16384][512]
    const size_t OFF_Z     = 16777216;
    const size_t OFF_QS    = 33554432;
    const size_t OFF_E     = 50331648;           // 16 MiB bf16 E
    const size_t OFF_RV    = 67108864;           // 512 KiB f32
    const size_t OFF_L     = 67633152;           // 8 KiB f32 lsum
    const size_t OFF_TAB   = 67641344;           // 1 MiB tab_pj
    const size_t OFF_TABJP = 68689920;           // 1 MiB tab_jp
    const size_t OFF_WT    = 69738496;           // Wtcat 1536x512 bf16 = 1.5 MiB
    const size_t OFF_WKR   = 71311360;           // 512x512 bf16
    const size_t OFF_BIAS  = 71835648;           // 1536 f32
    const size_t OFF_CANON = 71841792;           // 18,944,000 B
    const size_t OFF_FLAG  = OFF_CANON + 18944000;
    const size_t NEED      = OFF_FLAG + 16;      // ~90.8 MB
    if (ws_size < NEED) return;

    char* ws = (char*)d_ws;
    ushort* skip  = (ushort*)(ws + OFF_SK);
    ushort* z     = (ushort*)(ws + OFF_Z);
    ushort* qs    = (ushort*)(ws + OFF_QS);
    ushort* E     = (ushort*)(ws + OFF_E);
    float*  rV    = (float*)(ws + OFF_RV);
    float*  lsum  = (float*)(ws + OFF_L);
    float2* tabpj = (float2*)(ws + OFF_TAB);
    float2* tabjp = (float2*)(ws + OFF_TABJP);
    ushort* Wtcat = (ushort*)(ws + OFF_WT);
    ushort* Wkr   = (ushort*)(ws + OFF_WKR);
    float*  bias  = (float*)(ws + OFF_BIAS);
    ushort* canon = (ushort*)(ws + OFF_CANON);
    int*    flag  = (int*)(ws + OFF_FLAG);

    const ushort* Xc   = canon;
    const ushort* Wqc  = canon + SEG1;
    const ushort* bqc  = canon + SEG2;
    const ushort* Wkc  = canon + SEG3;
    const ushort* Wskc = canon + SEG5;
    const ushort* bskc = canon + SEG6;
    const ushort* Wzc  = canon + SEG7;
    const ushort* bzc  = canon + SEG8;
    const ushort* RPc  = canon + SEG9;

    sniff_k<<<1, 256, 0, stream>>>((const uint*)d_in[0], flag);
    prep0_k<<<5268, 256, 0, stream>>>(d_in[0], d_in[1], d_in[2], d_in[3], d_in[4],
                                      d_in[5], d_in[6], d_in[7], d_in[8], d_in[9],
                                      flag, canon, tabpj, tabjp, rV, lsum);
    prep1_k<<<257, 256, 0, stream>>>(Wskc, Wzc, Wqc, Wkc, RPc, bqc, bskc, bzc,
                                     Wtcat, Wkr, bias);
    big_k<<<2048, 256, 0, stream>>>(Xc, Wtcat, bias, Wkr, skip, z, qs, E, lsum);
    router_v_k<<<dim3(32, 32), 256, 0, stream>>>(E, lsum, Xc, tabjp, rV);
    final_attn_k<<<dim3(64, 8, 4), 256, 0, stream>>>(qs, rV, tabpj, skip, z, flag, d_out);
}